// Round 1
// baseline (9089.217 us; speedup 1.0000x reference)
//
#include <hip/hip_runtime.h>
#include <hip/hip_bf16.h>
#include <math.h>

#define D_MODEL 384
#define D_INNER 768
#define D_STATE 16
#define DT_RANK 24
#define NXP 56          // DT_RANK + 2*D_STATE
#define LTOK 196
#define BSZ 16
#define NROW 3136       // BSZ * LTOK
#define NDEPTH 24
#define NCLS 1000

constexpr float kSqrtC   = 0.70710678118654752440f;
constexpr float kMaxNorm = 0.95f / 0.70710678118654752440f;   // 1.3435029...

__device__ __forceinline__ float clampf(float x, float lo, float hi) {
  return fminf(fmaxf(x, lo), hi);
}

// block=128 sum-reduce with broadcast. Leading __syncthreads guards smem reuse.
__device__ __forceinline__ float blockSum128(float v, float* sm) {
#pragma unroll
  for (int o = 32; o > 0; o >>= 1) v += __shfl_down(v, o, 64);
  __syncthreads();
  if ((threadIdx.x & 63) == 0) sm[threadIdx.x >> 6] = v;
  __syncthreads();
  return sm[0] + sm[1];
}

// ---------------------------------------------------------------- im2col ----
__global__ __launch_bounds__(256) void k_im2col(const float* __restrict__ x,
                                                float* __restrict__ P) {
  size_t idx = (size_t)blockIdx.x * 256 + threadIdx.x;
  if (idx >= (size_t)NROW * 768) return;
  int k = (int)(idx % 768);
  int r = (int)(idx / 768);
  int b = r / LTOK, t = r % LTOK;
  int hp = t / 14, wp = t % 14;
  int c = k / 256, rem = k % 256, i = rem / 16, j = rem % 16;
  P[idx] = x[(((size_t)(b * 3 + c) * 224) + hp * 16 + i) * 224 + wp * 16 + j];
}

// ------------------------------------------------- generic f32 GEMM A*W^T ---
// A (M,K) rm, W (N,K) rm, C (M,N) rm. M%64==0, N%64==0, K%16==0.
__global__ __launch_bounds__(256) void k_gemm(const float* __restrict__ A,
                                              const float* __restrict__ W,
                                              const float* __restrict__ bias,
                                              float* __restrict__ Cm,
                                              int M, int N, int K) {
  __shared__ float As[16][68];
  __shared__ float Ws[16][68];
  const int tid = threadIdx.x;
  const int m0 = blockIdx.x * 64;
  const int n0 = blockIdx.y * 64;
  const int lr = tid >> 2;
  const int lk = (tid & 3) << 2;
  const int r0 = (tid >> 4) << 2;
  const int c0 = (tid & 15) << 2;
  float acc[4][4] = {};
  const float* ap = A + (size_t)(m0 + lr) * K + lk;
  const float* wp = W + (size_t)(n0 + lr) * K + lk;
  for (int k0 = 0; k0 < K; k0 += 16) {
    float4 av = *(const float4*)(ap + k0);
    float4 wv = *(const float4*)(wp + k0);
    As[lk + 0][lr] = av.x; As[lk + 1][lr] = av.y;
    As[lk + 2][lr] = av.z; As[lk + 3][lr] = av.w;
    Ws[lk + 0][lr] = wv.x; Ws[lk + 1][lr] = wv.y;
    Ws[lk + 2][lr] = wv.z; Ws[lk + 3][lr] = wv.w;
    __syncthreads();
#pragma unroll
    for (int kk = 0; kk < 16; kk++) {
      const float4 a4 = *(const float4*)&As[kk][r0];
      const float4 b4 = *(const float4*)&Ws[kk][c0];
      float aa[4] = {a4.x, a4.y, a4.z, a4.w};
      float bb[4] = {b4.x, b4.y, b4.z, b4.w};
#pragma unroll
      for (int i = 0; i < 4; i++)
#pragma unroll
        for (int j = 0; j < 4; j++) acc[i][j] = fmaf(aa[i], bb[j], acc[i][j]);
    }
    __syncthreads();
  }
  float bj[4] = {0.f, 0.f, 0.f, 0.f};
  if (bias) {
#pragma unroll
    for (int j = 0; j < 4; j++) bj[j] = bias[n0 + c0 + j];
  }
#pragma unroll
  for (int i = 0; i < 4; i++) {
    float4 o;
    o.x = acc[i][0] + bj[0]; o.y = acc[i][1] + bj[1];
    o.z = acc[i][2] + bj[2]; o.w = acc[i][3] + bj[3];
    *(float4*)&Cm[(size_t)(m0 + r0 + i) * N + n0 + c0] = o;
  }
}

// --------------------------------------------- stem a: expmap0(tokens) ------
__global__ __launch_bounds__(128) void k_stem_a(const float* __restrict__ tok,
                                                float* __restrict__ h,
                                                float* __restrict__ xn) {
  __shared__ float sm[2];
  const int r = blockIdx.x, tid = threadIdx.x;
  float v[3];
#pragma unroll
  for (int j = 0; j < 3; j++) v[j] = tok[(size_t)r * D_MODEL + tid + j * 128];
  float s = blockSum128(v[0] * v[0] + v[1] * v[1] + v[2] * v[2], sm);
  float n = sqrtf(s + 1e-15f);
  float nc = clampf(n, 1e-8f, 5.f);
  float ke = tanhf(kSqrtC * nc) / (kSqrtC * nc);
  float rn = sqrtf(ke * ke * s + 1e-15f);
  float sc = rn > kMaxNorm ? kMaxNorm / rn : 1.f;
  float kk = ke * sc;
#pragma unroll
  for (int j = 0; j < 3; j++) h[(size_t)r * D_MODEL + tid + j * 128] = kk * v[j];
  if (tid == 0) xn[r] = fmaxf(sqrtf(kk * kk * s + 1e-15f), 1e-8f);
}

// --- stem b: mobius_matvec tail + mobius_add(hyp_b) + hyp_LN + pos + expmap -
__global__ __launch_bounds__(128) void k_stem_b(
    const float* __restrict__ mx, const float* __restrict__ xn,
    const float* __restrict__ hyp_b, const float* __restrict__ pe_g,
    const float* __restrict__ pe_b, const float* __restrict__ pos,
    float* __restrict__ outh) {
  __shared__ float sm[2];
  const int r = blockIdx.x, tid = threadIdx.x;
  const int t = r % LTOK;
  float mv[3], bv[3];
  int dd[3];
#pragma unroll
  for (int j = 0; j < 3; j++) {
    dd[j] = tid + j * 128;
    mv[j] = mx[(size_t)r * D_MODEL + dd[j]];
    bv[j] = hyp_b[dd[j]];
  }
  float smx = blockSum128(mv[0] * mv[0] + mv[1] * mv[1] + mv[2] * mv[2], sm);
  float mxn = fmaxf(sqrtf(smx + 1e-15f), 1e-8f);
  float xnv = xn[r];
  float tt = tanhf(mxn / xnv * atanhf(fminf(kSqrtC * xnv, 1.f - 1e-5f)));
  float kres = tt / (mxn * kSqrtC);
  float res[3];
#pragma unroll
  for (int j = 0; j < 3; j++) res[j] = kres * mv[j];
  float xy = blockSum128(res[0] * bv[0] + res[1] * bv[1] + res[2] * bv[2], sm);
  float y2 = blockSum128(bv[0] * bv[0] + bv[1] * bv[1] + bv[2] * bv[2], sm);
  float x2 = kres * kres * smx;
  float al = 1.f + xy + 0.5f * y2;          // 1 + 2c*xy + c*y2, c=0.5
  float be = 1.f - 0.5f * x2;
  float den = fmaxf(1.f + xy + 0.25f * x2 * y2, 1e-15f);
  float h1[3];
#pragma unroll
  for (int j = 0; j < 3; j++) h1[j] = (al * res[j] + be * bv[j]) / den;
  // hyp_layernorm(h1, pe_g, pe_b)
  float s1 = blockSum128(h1[0] * h1[0] + h1[1] * h1[1] + h1[2] * h1[2], sm);
  float n1 = sqrtf(s1 + 1e-15f);
  float nc1 = clampf(n1, 1e-8f, kMaxNorm);
  float kl = atanhf(fminf(kSqrtC * nc1, 0.95f)) / (kSqrtC * nc1);
  float tl[3];
#pragma unroll
  for (int j = 0; j < 3; j++) tl[j] = kl * h1[j];
  float mean = blockSum128(tl[0] + tl[1] + tl[2], sm) * (1.f / 384.f);
  float dv = 0.f;
#pragma unroll
  for (int j = 0; j < 3; j++) { float d = tl[j] - mean; dv += d * d; }
  float var = blockSum128(dv, sm) * (1.f / 383.f);
  float inv = 1.f / (sqrtf(var) + 1e-5f);
  float g[3];
#pragma unroll
  for (int j = 0; j < 3; j++)
    g[j] = (tl[j] - mean) * inv * pe_g[dd[j]] + pe_b[dd[j]];
  float sg = blockSum128(g[0] * g[0] + g[1] * g[1] + g[2] * g[2], sm);
  float ng = sqrtf(sg + 1e-15f);
  float nc2 = clampf(ng, 1e-8f, 5.f);
  float ke = tanhf(kSqrtC * nc2) / (kSqrtC * nc2);
  float rn = sqrtf(ke * ke * sg + 1e-15f);
  float sc = rn > kMaxNorm ? kMaxNorm / rn : 1.f;
  float kk = ke * sc;                        // h2 = kk*g
  // logmap0(h2) + pos, then expmap0
  float s2 = kk * kk * sg;
  float n3 = sqrtf(s2 + 1e-15f);
  float nc3 = clampf(n3, 1e-8f, kMaxNorm);
  float kl2 = atanhf(fminf(kSqrtC * nc3, 0.95f)) / (kSqrtC * nc3);
  float v[3];
#pragma unroll
  for (int j = 0; j < 3; j++)
    v[j] = kl2 * kk * g[j] + pos[(size_t)t * D_MODEL + dd[j]];
  float sv = blockSum128(v[0] * v[0] + v[1] * v[1] + v[2] * v[2], sm);
  float nv = sqrtf(sv + 1e-15f);
  float nc4 = clampf(nv, 1e-8f, 5.f);
  float ke2 = tanhf(kSqrtC * nc4) / (kSqrtC * nc4);
  float rn2 = sqrtf(ke2 * ke2 * sv + 1e-15f);
  float sc2 = rn2 > kMaxNorm ? kMaxNorm / rn2 : 1.f;
#pragma unroll
  for (int j = 0; j < 3; j++)
    outh[(size_t)r * D_MODEL + dd[j]] = ke2 * sc2 * v[j];
}

// -------- residual accumulate + hyp_layernorm (optionally emit logmap0) -----
__global__ __launch_bounds__(128) void k_resln(
    const float* __restrict__ hid, const float* __restrict__ res_in,
    float* __restrict__ res_out, const float* __restrict__ g_,
    const float* __restrict__ b_, float* __restrict__ outp, int first,
    int out_logmap) {
  __shared__ float sm[2];
  const int r = blockIdx.x, tid = threadIdx.x;
  float v[3];
  int dd[3];
#pragma unroll
  for (int j = 0; j < 3; j++) {
    dd[j] = tid + j * 128;
    size_t idx = (size_t)r * D_MODEL + dd[j];
    v[j] = hid[idx] + (first ? 0.f : res_in[idx]);
    res_out[idx] = v[j];
  }
  float s = blockSum128(v[0] * v[0] + v[1] * v[1] + v[2] * v[2], sm);
  float n = sqrtf(s + 1e-15f);
  float nc = clampf(n, 1e-8f, kMaxNorm);
  float kl = atanhf(fminf(kSqrtC * nc, 0.95f)) / (kSqrtC * nc);
  float t[3];
#pragma unroll
  for (int j = 0; j < 3; j++) t[j] = kl * v[j];
  float mean = blockSum128(t[0] + t[1] + t[2], sm) * (1.f / 384.f);
  float dv = 0.f;
#pragma unroll
  for (int j = 0; j < 3; j++) { float d = t[j] - mean; dv += d * d; }
  float var = blockSum128(dv, sm) * (1.f / 383.f);
  float inv = 1.f / (sqrtf(var) + 1e-5f);
  float g[3];
#pragma unroll
  for (int j = 0; j < 3; j++)
    g[j] = (t[j] - mean) * inv * g_[dd[j]] + b_[dd[j]];
  float sg = blockSum128(g[0] * g[0] + g[1] * g[1] + g[2] * g[2], sm);
  float ng = sqrtf(sg + 1e-15f);
  float nc2 = clampf(ng, 1e-8f, 5.f);
  float ke = tanhf(kSqrtC * nc2) / (kSqrtC * nc2);
  float rn = sqrtf(ke * ke * sg + 1e-15f);
  float sc = rn > kMaxNorm ? kMaxNorm / rn : 1.f;
  float kk = ke * sc;
  if (!out_logmap) {
#pragma unroll
    for (int j = 0; j < 3; j++) outp[(size_t)r * D_MODEL + dd[j]] = kk * g[j];
  } else {
    float s2 = kk * kk * sg;
    float n3 = sqrtf(s2 + 1e-15f);
    float nc3 = clampf(n3, 1e-8f, kMaxNorm);
    float kl2 = atanhf(fminf(kSqrtC * nc3, 0.95f)) / (kSqrtC * nc3);
#pragma unroll
    for (int j = 0; j < 3; j++)
      outp[(size_t)r * D_MODEL + dd[j]] = kl2 * kk * g[j];
  }
}

// ---- conv1d(k=4, causal) + SiLU + x_proj + dt_proj + softplus, per token ---
__global__ __launch_bounds__(256) void k_convx(
    const float* __restrict__ xz, const float* __restrict__ cw,
    const float* __restrict__ cb, const float* __restrict__ xw,
    const float* __restrict__ dtw, const float* __restrict__ dtbias,
    float* __restrict__ u, float* __restrict__ dbl, float* __restrict__ dtbuf) {
  __shared__ float su[D_INNER];
  __shared__ float sdbl[NXP];
  const int r = blockIdx.x;
  const int b = r / LTOK, l = r % LTOK;
  const int tid = threadIdx.x;
#pragma unroll
  for (int j = 0; j < 3; j++) {
    int d = tid + j * 256;
    float acc = cb[d];
#pragma unroll
    for (int k = 0; k < 4; k++) {
      int ll = l - 3 + k;
      if (ll >= 0)
        acc += cw[d * 4 + k] * xz[(size_t)(b * LTOK + ll) * (2 * D_INNER) + d];
    }
    float uv = acc / (1.f + expf(-acc));   // silu
    su[d] = uv;
    u[(size_t)r * D_INNER + d] = uv;
  }
  __syncthreads();
  // x_proj: 224 threads, 4 partials per output
  const int nn = tid >> 2, p = tid & 3;
  float partial = 0.f;
  if (tid < 224) {
    const float* wrow = xw + (size_t)nn * D_INNER;
    for (int k = p; k < D_INNER; k += 4) partial += su[k] * wrow[k];
  }
  partial += __shfl_xor(partial, 1, 64);
  partial += __shfl_xor(partial, 2, 64);
  if (tid < 224 && p == 0) {
    sdbl[nn] = partial;
    dbl[(size_t)r * NXP + nn] = partial;
  }
  __syncthreads();
  // dt_proj + softplus
#pragma unroll
  for (int j = 0; j < 3; j++) {
    int d = tid + j * 256;
    float acc = dtbias[d];
#pragma unroll
    for (int k = 0; k < DT_RANK; k++) acc += sdbl[k] * dtw[d * DT_RANK + k];
    float sp = (acc > 20.f) ? acc : log1pf(expf(acc));
    dtbuf[(size_t)r * D_INNER + d] = sp;
  }
}

// ------------- selective scan, (b, d, n)-parallel, 16 lanes per channel -----
__global__ __launch_bounds__(256) void k_scan(
    const float* __restrict__ u, const float* __restrict__ dtbuf,
    const float* __restrict__ dbl, const float* __restrict__ xz,
    const float* __restrict__ A_log, const float* __restrict__ Dp,
    float* __restrict__ yf) {
  const int tid = threadIdx.x;
  const int n = tid & 15, dl = tid >> 4;
  const int d = blockIdx.x * 16 + dl;
  const int b = blockIdx.y;
  const float a = -expf(A_log[(size_t)d * D_STATE + n]);
  const float Dv = Dp[d];
  float h = 0.f;
  const size_t base = (size_t)b * LTOK;
  for (int l = 0; l < LTOK; l++) {
    size_t r = base + l;
    float dtv = dtbuf[r * D_INNER + d];
    float uv = u[r * D_INNER + d];
    float Bv = dbl[r * NXP + DT_RANK + n];
    float Cv = dbl[r * NXP + DT_RANK + D_STATE + n];
    h = expf(dtv * a) * h + dtv * Bv * uv;
    float y = h * Cv;
    y += __shfl_xor(y, 1, 64);
    y += __shfl_xor(y, 2, 64);
    y += __shfl_xor(y, 4, 64);
    y += __shfl_xor(y, 8, 64);
    if (n == 0) {
      float zv = xz[r * (2 * D_INNER) + D_INNER + d];
      float yv = (y + Dv * uv) * (zv / (1.f + expf(-zv)));
      yf[r * D_INNER + d] = yv;
    }
  }
}

// ---------------------- mean over L of logmap0 rows + expmap0 ---------------
__global__ __launch_bounds__(128) void k_pool(const float* __restrict__ tl,
                                              float* __restrict__ pooled,
                                              float* __restrict__ x2v) {
  __shared__ float sm[2];
  const int b = blockIdx.x, tid = threadIdx.x;
  float m[3] = {0.f, 0.f, 0.f};
  for (int l = 0; l < LTOK; l++) {
    size_t row = ((size_t)b * LTOK + l) * D_MODEL;
#pragma unroll
    for (int j = 0; j < 3; j++) m[j] += tl[row + tid + j * 128];
  }
#pragma unroll
  for (int j = 0; j < 3; j++) m[j] *= (1.f / (float)LTOK);
  float s = blockSum128(m[0] * m[0] + m[1] * m[1] + m[2] * m[2], sm);
  float n = sqrtf(s + 1e-15f);
  float nc = clampf(n, 1e-8f, 5.f);
  float ke = tanhf(kSqrtC * nc) / (kSqrtC * nc);
  float rn = sqrtf(ke * ke * s + 1e-15f);
  float sc = rn > kMaxNorm ? kMaxNorm / rn : 1.f;
  float kk = ke * sc;
  float p[3];
#pragma unroll
  for (int j = 0; j < 3; j++) {
    p[j] = kk * m[j];
    pooled[(size_t)b * D_MODEL + tid + j * 128] = p[j];
  }
  float s2 = blockSum128(p[0] * p[0] + p[1] * p[1] + p[2] * p[2], sm);
  if (tid == 0) x2v[b] = s2;
}

// ------------------- hyperbolic distance head over prototypes ---------------
__global__ __launch_bounds__(256) void k_head(const float* __restrict__ pooled,
                                              const float* __restrict__ protos,
                                              const float* __restrict__ x2v,
                                              float* __restrict__ out) {
  __shared__ float sp[D_MODEL];
  const int b = blockIdx.y;
  const int c = blockIdx.x * 256 + threadIdx.x;
  for (int j = threadIdx.x; j < D_MODEL; j += 256)
    sp[j] = pooled[(size_t)b * D_MODEL + j];
  __syncthreads();
  if (c >= NCLS) return;
  const float* pr = protos + (size_t)c * D_MODEL;
  float dotv = 0.f, y2 = 0.f;
  for (int k = 0; k < D_MODEL; k++) {
    float w = pr[k];
    dotv += sp[k] * w;
    y2 += w * w;
  }
  float x2 = x2v[b];
  float xy = -dotv;                       // <a,b>, a = -pooled
  float al = 1.f + xy + 0.5f * y2;        // 1 + 2c*xy + c*y2
  float be = 1.f - 0.5f * x2;
  float num2 = al * al * x2 + 2.f * al * be * xy + be * be * y2;
  float den = fmaxf(1.f + xy + 0.25f * x2 * y2, 1e-15f);
  float r2 = num2 / (den * den) + 1e-15f;
  float dn = fminf(kSqrtC * sqrtf(r2), 1.f - 1e-5f);
  out[(size_t)b * NCLS + c] = -(2.f / kSqrtC) * atanhf(dn);
}

// ---------------------------------------------------------------------------
extern "C" void kernel_launch(void* const* d_in, const int* in_sizes, int n_in,
                              void* d_out, int out_size, void* d_ws,
                              size_t ws_size, hipStream_t stream) {
  const float* x        = (const float*)d_in[0];
  const float* patch_w  = (const float*)d_in[1];
  const float* patch_b  = (const float*)d_in[2];
  const float* hyp_w    = (const float*)d_in[3];
  const float* hyp_b    = (const float*)d_in[4];
  const float* pe_gamma = (const float*)d_in[5];
  const float* pe_beta  = (const float*)d_in[6];
  const float* pos      = (const float*)d_in[7];
  const float* in_w     = (const float*)d_in[8];
  const float* conv_w   = (const float*)d_in[9];
  const float* conv_b   = (const float*)d_in[10];
  const float* xp_w     = (const float*)d_in[11];
  const float* dt_w     = (const float*)d_in[12];
  const float* dt_bias  = (const float*)d_in[13];
  const float* A_log    = (const float*)d_in[14];
  const float* Dp       = (const float*)d_in[15];
  const float* out_w    = (const float*)d_in[16];
  const float* gamma    = (const float*)d_in[17];
  const float* beta     = (const float*)d_in[18];
  const float* gamma_f  = (const float*)d_in[19];
  const float* beta_f   = (const float*)d_in[20];
  const float* protos   = (const float*)d_in[21];
  float* out = (float*)d_out;

  // workspace layout (floats); ~63.4 MB total
  float* base   = (float*)d_ws;
  float* hidden = base;
  float* resid  = hidden + (size_t)NROW * D_MODEL;
  float* hn     = resid  + (size_t)NROW * D_MODEL;
  float* xz     = hn     + (size_t)NROW * D_MODEL;
  float* u      = xz     + (size_t)NROW * 2 * D_INNER;
  float* dtbuf  = u      + (size_t)NROW * D_INNER;
  float* yf     = dtbuf  + (size_t)NROW * D_INNER;
  float* dbl    = yf     + (size_t)NROW * D_INNER;
  float* xn     = dbl    + (size_t)NROW * NXP;
  float* pooled = xn     + NROW;
  float* x2v    = pooled + (size_t)BSZ * D_MODEL;
  // stem-phase aliases (dead regions during stem)
  float* P      = xz;     // 3136 x 768 im2col
  float* tokens = u;      // 3136 x 384
  float* mx     = dtbuf;  // 3136 x 384

  // stem
  k_im2col<<<dim3((NROW * 768) / 256), dim3(256), 0, stream>>>(x, P);
  k_gemm<<<dim3(NROW / 64, D_MODEL / 64), dim3(256), 0, stream>>>(
      P, patch_w, patch_b, tokens, NROW, D_MODEL, 768);
  k_stem_a<<<dim3(NROW), dim3(128), 0, stream>>>(tokens, hidden, xn);
  k_gemm<<<dim3(NROW / 64, D_MODEL / 64), dim3(256), 0, stream>>>(
      hidden, hyp_w, nullptr, mx, NROW, D_MODEL, D_MODEL);
  k_stem_b<<<dim3(NROW), dim3(128), 0, stream>>>(mx, xn, hyp_b, pe_gamma,
                                                 pe_beta, pos, hidden);
  // layers
  for (int i = 0; i < NDEPTH; i++) {
    k_resln<<<dim3(NROW), dim3(128), 0, stream>>>(
        hidden, resid, resid, gamma + (size_t)i * D_MODEL,
        beta + (size_t)i * D_MODEL, hn, i == 0 ? 1 : 0, 0);
    k_gemm<<<dim3(NROW / 64, (2 * D_INNER) / 64), dim3(256), 0, stream>>>(
        hn, in_w + (size_t)i * 2 * D_INNER * D_MODEL, nullptr, xz, NROW,
        2 * D_INNER, D_MODEL);
    k_convx<<<dim3(NROW), dim3(256), 0, stream>>>(
        xz, conv_w + (size_t)i * D_INNER * 4, conv_b + (size_t)i * D_INNER,
        xp_w + (size_t)i * NXP * D_INNER,
        dt_w + (size_t)i * D_INNER * DT_RANK, dt_bias + (size_t)i * D_INNER,
        u, dbl, dtbuf);
    k_scan<<<dim3(D_INNER / 16, BSZ), dim3(256), 0, stream>>>(
        u, dtbuf, dbl, xz, A_log + (size_t)i * D_INNER * D_STATE,
        Dp + (size_t)i * D_INNER, yf);
    k_gemm<<<dim3(NROW / 64, D_MODEL / 64), dim3(256), 0, stream>>>(
        yf, out_w + (size_t)i * D_MODEL * D_INNER, nullptr, hidden, NROW,
        D_MODEL, D_INNER);
  }
  // head
  k_resln<<<dim3(NROW), dim3(128), 0, stream>>>(hidden, resid, resid, gamma_f,
                                                beta_f, hn, 0, 1);
  k_pool<<<dim3(BSZ), dim3(128), 0, stream>>>(hn, pooled, x2v);
  k_head<<<dim3((NCLS + 255) / 256, BSZ), dim3(256), 0, stream>>>(pooled,
                                                                  protos, x2v,
                                                                  out);
}

// Round 2
// 7571.245 us; speedup vs baseline: 1.2005x; 1.2005x over previous
//
#include <hip/hip_runtime.h>
#include <hip/hip_bf16.h>
#include <math.h>

#define D_MODEL 384
#define D_INNER 768
#define D_STATE 16
#define DT_RANK 24
#define NXP 56          // DT_RANK + 2*D_STATE
#define LTOK 196
#define BSZ 16
#define NROW 3136       // BSZ * LTOK
#define NDEPTH 24
#define NCLS 1000

constexpr float kSqrtC   = 0.70710678118654752440f;
constexpr float kMaxNorm = 0.95f / 0.70710678118654752440f;   // 1.3435029...

typedef short  bf16x8 __attribute__((ext_vector_type(8)));
typedef float  f32x4  __attribute__((ext_vector_type(4)));

__device__ __forceinline__ float clampf(float x, float lo, float hi) {
  return fminf(fmaxf(x, lo), hi);
}

// f32 -> bf16 (RNE) as raw short
__device__ __forceinline__ short f2bf(float f) {
  union { float f; unsigned u; } v; v.f = f;
  unsigned r = (v.u + 0x7FFFu + ((v.u >> 16) & 1u)) >> 16;
  return (short)r;
}

// block=128 sum-reduce with broadcast. Leading __syncthreads guards smem reuse.
__device__ __forceinline__ float blockSum128(float v, float* sm) {
#pragma unroll
  for (int o = 32; o > 0; o >>= 1) v += __shfl_down(v, o, 64);
  __syncthreads();
  if ((threadIdx.x & 63) == 0) sm[threadIdx.x >> 6] = v;
  __syncthreads();
  return sm[0] + sm[1];
}

// ---------------------------------------------------------------- im2col ----
__global__ __launch_bounds__(256) void k_im2col(const float* __restrict__ x,
                                                float* __restrict__ P) {
  size_t idx = (size_t)blockIdx.x * 256 + threadIdx.x;
  if (idx >= (size_t)NROW * 768) return;
  int k = (int)(idx % 768);
  int r = (int)(idx / 768);
  int b = r / LTOK, t = r % LTOK;
  int hp = t / 14, wp = t % 14;
  int c = k / 256, rem = k % 256, i = rem / 16, j = rem % 16;
  P[idx] = x[(((size_t)(b * 3 + c) * 224) + hp * 16 + i) * 224 + wp * 16 + j];
}

// --------------------------------------- bf16 MFMA GEMM: C = A * W^T (+b) ---
// A (M,K) f32 rm, W (N,K) f32 rm, C (M,N) f32 rm. M%64==0, N%64==0, K%32==0.
// f32->bf16 conversion happens in the LDS staging path (RNE).
// Tile 64x64x32, 256 threads = 4 waves, each wave owns a 32x32 quadrant via
// 2x2 of v_mfma_f32_16x16x32_bf16. LDS row stride 40 shorts (80 B) to spread
// banks (rows hit bank-start r*20 mod 32 -> 2-way max = free per m136).
#define LDA 40
__global__ __launch_bounds__(256) void k_gemm_bf16(
    const float* __restrict__ A, const float* __restrict__ W,
    const float* __restrict__ bias, float* __restrict__ Cm,
    int M, int N, int K) {
  __shared__ short As[64 * LDA];
  __shared__ short Ws[64 * LDA];
  const int tid = threadIdx.x;
  const int m0 = blockIdx.x * 64;
  const int n0 = blockIdx.y * 64;
  const int lane = tid & 63;
  const int wave = tid >> 6;
  const int wm = wave & 1, wn = wave >> 1;
  const int lm = lane & 15;           // m (or n) within a 16-tile
  const int quad = lane >> 4;         // k-chunk selector / C-row group
  const int srow = tid >> 2;          // staging row 0..63
  const int sseg = tid & 3;           // staging 8-float segment

  f32x4 acc[2][2];
#pragma unroll
  for (int i = 0; i < 2; i++)
#pragma unroll
    for (int j = 0; j < 2; j++) acc[i][j] = (f32x4){0.f, 0.f, 0.f, 0.f};

  const float* ap = A + (size_t)(m0 + srow) * K + sseg * 8;
  const float* wp = W + (size_t)(n0 + srow) * K + sseg * 8;

  for (int k0 = 0; k0 < K; k0 += 32) {
    float4 a0 = *(const float4*)(ap + k0);
    float4 a1 = *(const float4*)(ap + k0 + 4);
    float4 w0 = *(const float4*)(wp + k0);
    float4 w1 = *(const float4*)(wp + k0 + 4);
    short4 sa0 = {f2bf(a0.x), f2bf(a0.y), f2bf(a0.z), f2bf(a0.w)};
    short4 sa1 = {f2bf(a1.x), f2bf(a1.y), f2bf(a1.z), f2bf(a1.w)};
    short4 sw0 = {f2bf(w0.x), f2bf(w0.y), f2bf(w0.z), f2bf(w0.w)};
    short4 sw1 = {f2bf(w1.x), f2bf(w1.y), f2bf(w1.z), f2bf(w1.w)};
    __syncthreads();  // guard LDS reuse from previous iter's reads
    *(short4*)&As[srow * LDA + sseg * 8]     = sa0;
    *(short4*)&As[srow * LDA + sseg * 8 + 4] = sa1;
    *(short4*)&Ws[srow * LDA + sseg * 8]     = sw0;
    *(short4*)&Ws[srow * LDA + sseg * 8 + 4] = sw1;
    __syncthreads();
    bf16x8 af[2], bf[2];
#pragma unroll
    for (int i = 0; i < 2; i++) {
      af[i] = *(bf16x8*)&As[(wm * 32 + i * 16 + lm) * LDA + quad * 8];
      bf[i] = *(bf16x8*)&Ws[(wn * 32 + i * 16 + lm) * LDA + quad * 8];
    }
#pragma unroll
    for (int i = 0; i < 2; i++)
#pragma unroll
      for (int j = 0; j < 2; j++)
        acc[i][j] = __builtin_amdgcn_mfma_f32_16x16x32_bf16(af[i], bf[j],
                                                            acc[i][j], 0, 0, 0);
  }
  // epilogue: C/D layout col=lane&15, row=quad*4+reg
#pragma unroll
  for (int i = 0; i < 2; i++) {
#pragma unroll
    for (int j = 0; j < 2; j++) {
      int cg = n0 + wn * 32 + j * 16 + lm;
      float bj = bias ? bias[cg] : 0.f;
#pragma unroll
      for (int reg = 0; reg < 4; reg++) {
        int rg = m0 + wm * 32 + i * 16 + quad * 4 + reg;
        Cm[(size_t)rg * N + cg] = acc[i][j][reg] + bj;
      }
    }
  }
}

// --------------------------------------------- stem a: expmap0(tokens) ------
__global__ __launch_bounds__(128) void k_stem_a(const float* __restrict__ tok,
                                                float* __restrict__ h,
                                                float* __restrict__ xn) {
  __shared__ float sm[2];
  const int r = blockIdx.x, tid = threadIdx.x;
  float v[3];
#pragma unroll
  for (int j = 0; j < 3; j++) v[j] = tok[(size_t)r * D_MODEL + tid + j * 128];
  float s = blockSum128(v[0] * v[0] + v[1] * v[1] + v[2] * v[2], sm);
  float n = sqrtf(s + 1e-15f);
  float nc = clampf(n, 1e-8f, 5.f);
  float ke = tanhf(kSqrtC * nc) / (kSqrtC * nc);
  float rn = sqrtf(ke * ke * s + 1e-15f);
  float sc = rn > kMaxNorm ? kMaxNorm / rn : 1.f;
  float kk = ke * sc;
#pragma unroll
  for (int j = 0; j < 3; j++) h[(size_t)r * D_MODEL + tid + j * 128] = kk * v[j];
  if (tid == 0) xn[r] = fmaxf(sqrtf(kk * kk * s + 1e-15f), 1e-8f);
}

// --- stem b: mobius_matvec tail + mobius_add(hyp_b) + hyp_LN + pos + expmap -
__global__ __launch_bounds__(128) void k_stem_b(
    const float* __restrict__ mx, const float* __restrict__ xn,
    const float* __restrict__ hyp_b, const float* __restrict__ pe_g,
    const float* __restrict__ pe_b, const float* __restrict__ pos,
    float* __restrict__ outh) {
  __shared__ float sm[2];
  const int r = blockIdx.x, tid = threadIdx.x;
  const int t = r % LTOK;
  float mv[3], bv[3];
  int dd[3];
#pragma unroll
  for (int j = 0; j < 3; j++) {
    dd[j] = tid + j * 128;
    mv[j] = mx[(size_t)r * D_MODEL + dd[j]];
    bv[j] = hyp_b[dd[j]];
  }
  float smx = blockSum128(mv[0] * mv[0] + mv[1] * mv[1] + mv[2] * mv[2], sm);
  float mxn = fmaxf(sqrtf(smx + 1e-15f), 1e-8f);
  float xnv = xn[r];
  float tt = tanhf(mxn / xnv * atanhf(fminf(kSqrtC * xnv, 1.f - 1e-5f)));
  float kres = tt / (mxn * kSqrtC);
  float res[3];
#pragma unroll
  for (int j = 0; j < 3; j++) res[j] = kres * mv[j];
  float xy = blockSum128(res[0] * bv[0] + res[1] * bv[1] + res[2] * bv[2], sm);
  float y2 = blockSum128(bv[0] * bv[0] + bv[1] * bv[1] + bv[2] * bv[2], sm);
  float x2 = kres * kres * smx;
  float al = 1.f + xy + 0.5f * y2;          // 1 + 2c*xy + c*y2, c=0.5
  float be = 1.f - 0.5f * x2;
  float den = fmaxf(1.f + xy + 0.25f * x2 * y2, 1e-15f);
  float h1[3];
#pragma unroll
  for (int j = 0; j < 3; j++) h1[j] = (al * res[j] + be * bv[j]) / den;
  // hyp_layernorm(h1, pe_g, pe_b)
  float s1 = blockSum128(h1[0] * h1[0] + h1[1] * h1[1] + h1[2] * h1[2], sm);
  float n1 = sqrtf(s1 + 1e-15f);
  float nc1 = clampf(n1, 1e-8f, kMaxNorm);
  float kl = atanhf(fminf(kSqrtC * nc1, 0.95f)) / (kSqrtC * nc1);
  float tl[3];
#pragma unroll
  for (int j = 0; j < 3; j++) tl[j] = kl * h1[j];
  float mean = blockSum128(tl[0] + tl[1] + tl[2], sm) * (1.f / 384.f);
  float dv = 0.f;
#pragma unroll
  for (int j = 0; j < 3; j++) { float d = tl[j] - mean; dv += d * d; }
  float var = blockSum128(dv, sm) * (1.f / 383.f);
  float inv = 1.f / (sqrtf(var) + 1e-5f);
  float g[3];
#pragma unroll
  for (int j = 0; j < 3; j++)
    g[j] = (tl[j] - mean) * inv * pe_g[dd[j]] + pe_b[dd[j]];
  float sg = blockSum128(g[0] * g[0] + g[1] * g[1] + g[2] * g[2], sm);
  float ng = sqrtf(sg + 1e-15f);
  float nc2 = clampf(ng, 1e-8f, 5.f);
  float ke = tanhf(kSqrtC * nc2) / (kSqrtC * nc2);
  float rn = sqrtf(ke * ke * sg + 1e-15f);
  float sc = rn > kMaxNorm ? kMaxNorm / rn : 1.f;
  float kk = ke * sc;                        // h2 = kk*g
  // logmap0(h2) + pos, then expmap0
  float s2 = kk * kk * sg;
  float n3 = sqrtf(s2 + 1e-15f);
  float nc3 = clampf(n3, 1e-8f, kMaxNorm);
  float kl2 = atanhf(fminf(kSqrtC * nc3, 0.95f)) / (kSqrtC * nc3);
  float v[3];
#pragma unroll
  for (int j = 0; j < 3; j++)
    v[j] = kl2 * kk * g[j] + pos[(size_t)t * D_MODEL + dd[j]];
  float sv = blockSum128(v[0] * v[0] + v[1] * v[1] + v[2] * v[2], sm);
  float nv = sqrtf(sv + 1e-15f);
  float nc4 = clampf(nv, 1e-8f, 5.f);
  float ke2 = tanhf(kSqrtC * nc4) / (kSqrtC * nc4);
  float rn2 = sqrtf(ke2 * ke2 * sv + 1e-15f);
  float sc2 = rn2 > kMaxNorm ? kMaxNorm / rn2 : 1.f;
#pragma unroll
  for (int j = 0; j < 3; j++)
    outh[(size_t)r * D_MODEL + dd[j]] = ke2 * sc2 * v[j];
}

// -------- residual accumulate + hyp_layernorm (optionally emit logmap0) -----
__global__ __launch_bounds__(128) void k_resln(
    const float* __restrict__ hid, const float* __restrict__ res_in,
    float* __restrict__ res_out, const float* __restrict__ g_,
    const float* __restrict__ b_, float* __restrict__ outp, int first,
    int out_logmap) {
  __shared__ float sm[2];
  const int r = blockIdx.x, tid = threadIdx.x;
  float v[3];
  int dd[3];
#pragma unroll
  for (int j = 0; j < 3; j++) {
    dd[j] = tid + j * 128;
    size_t idx = (size_t)r * D_MODEL + dd[j];
    v[j] = hid[idx] + (first ? 0.f : res_in[idx]);
    res_out[idx] = v[j];
  }
  float s = blockSum128(v[0] * v[0] + v[1] * v[1] + v[2] * v[2], sm);
  float n = sqrtf(s + 1e-15f);
  float nc = clampf(n, 1e-8f, kMaxNorm);
  float kl = atanhf(fminf(kSqrtC * nc, 0.95f)) / (kSqrtC * nc);
  float t[3];
#pragma unroll
  for (int j = 0; j < 3; j++) t[j] = kl * v[j];
  float mean = blockSum128(t[0] + t[1] + t[2], sm) * (1.f / 384.f);
  float dv = 0.f;
#pragma unroll
  for (int j = 0; j < 3; j++) { float d = t[j] - mean; dv += d * d; }
  float var = blockSum128(dv, sm) * (1.f / 383.f);
  float inv = 1.f / (sqrtf(var) + 1e-5f);
  float g[3];
#pragma unroll
  for (int j = 0; j < 3; j++)
    g[j] = (t[j] - mean) * inv * g_[dd[j]] + b_[dd[j]];
  float sg = blockSum128(g[0] * g[0] + g[1] * g[1] + g[2] * g[2], sm);
  float ng = sqrtf(sg + 1e-15f);
  float nc2 = clampf(ng, 1e-8f, 5.f);
  float ke = tanhf(kSqrtC * nc2) / (kSqrtC * nc2);
  float rn = sqrtf(ke * ke * sg + 1e-15f);
  float sc = rn > kMaxNorm ? kMaxNorm / rn : 1.f;
  float kk = ke * sc;
  if (!out_logmap) {
#pragma unroll
    for (int j = 0; j < 3; j++) outp[(size_t)r * D_MODEL + dd[j]] = kk * g[j];
  } else {
    float s2 = kk * kk * sg;
    float n3 = sqrtf(s2 + 1e-15f);
    float nc3 = clampf(n3, 1e-8f, kMaxNorm);
    float kl2 = atanhf(fminf(kSqrtC * nc3, 0.95f)) / (kSqrtC * nc3);
#pragma unroll
    for (int j = 0; j < 3; j++)
      outp[(size_t)r * D_MODEL + dd[j]] = kl2 * kk * g[j];
  }
}

// ---- conv1d(k=4, causal) + SiLU + x_proj + dt_proj + softplus, per token ---
__global__ __launch_bounds__(256) void k_convx(
    const float* __restrict__ xz, const float* __restrict__ cw,
    const float* __restrict__ cb, const float* __restrict__ xw,
    const float* __restrict__ dtw, const float* __restrict__ dtbias,
    float* __restrict__ u, float* __restrict__ dbl, float* __restrict__ dtbuf) {
  __shared__ float su[D_INNER];
  __shared__ float sdbl[NXP];
  const int r = blockIdx.x;
  const int b = r / LTOK, l = r % LTOK;
  const int tid = threadIdx.x;
#pragma unroll
  for (int j = 0; j < 3; j++) {
    int d = tid + j * 256;
    float acc = cb[d];
#pragma unroll
    for (int k = 0; k < 4; k++) {
      int ll = l - 3 + k;
      if (ll >= 0)
        acc += cw[d * 4 + k] * xz[(size_t)(b * LTOK + ll) * (2 * D_INNER) + d];
    }
    float uv = acc / (1.f + expf(-acc));   // silu
    su[d] = uv;
    u[(size_t)r * D_INNER + d] = uv;
  }
  __syncthreads();
  // x_proj: 224 threads, 4 partials per output
  const int nn = tid >> 2, p = tid & 3;
  float partial = 0.f;
  if (tid < 224) {
    const float* wrow = xw + (size_t)nn * D_INNER;
    for (int k = p; k < D_INNER; k += 4) partial += su[k] * wrow[k];
  }
  partial += __shfl_xor(partial, 1, 64);
  partial += __shfl_xor(partial, 2, 64);
  if (tid < 224 && p == 0) {
    sdbl[nn] = partial;
    dbl[(size_t)r * NXP + nn] = partial;
  }
  __syncthreads();
  // dt_proj + softplus
#pragma unroll
  for (int j = 0; j < 3; j++) {
    int d = tid + j * 256;
    float acc = dtbias[d];
#pragma unroll
    for (int k = 0; k < DT_RANK; k++) acc += sdbl[k] * dtw[d * DT_RANK + k];
    float sp = (acc > 20.f) ? acc : log1pf(expf(acc));
    dtbuf[(size_t)r * D_INNER + d] = sp;
  }
}

// ------------- selective scan, (b, d, n)-parallel, 16 lanes per channel -----
__global__ __launch_bounds__(256) void k_scan(
    const float* __restrict__ u, const float* __restrict__ dtbuf,
    const float* __restrict__ dbl, const float* __restrict__ xz,
    const float* __restrict__ A_log, const float* __restrict__ Dp,
    float* __restrict__ yf) {
  const int tid = threadIdx.x;
  const int n = tid & 15, dl = tid >> 4;
  const int d = blockIdx.x * 16 + dl;
  const int b = blockIdx.y;
  const float a = -expf(A_log[(size_t)d * D_STATE + n]);
  const float Dv = Dp[d];
  float h = 0.f;
  const size_t base = (size_t)b * LTOK;
  for (int l = 0; l < LTOK; l++) {
    size_t r = base + l;
    float dtv = dtbuf[r * D_INNER + d];
    float uv = u[r * D_INNER + d];
    float Bv = dbl[r * NXP + DT_RANK + n];
    float Cv = dbl[r * NXP + DT_RANK + D_STATE + n];
    h = expf(dtv * a) * h + dtv * Bv * uv;
    float y = h * Cv;
    y += __shfl_xor(y, 1, 64);
    y += __shfl_xor(y, 2, 64);
    y += __shfl_xor(y, 4, 64);
    y += __shfl_xor(y, 8, 64);
    if (n == 0) {
      float zv = xz[r * (2 * D_INNER) + D_INNER + d];
      float yv = (y + Dv * uv) * (zv / (1.f + expf(-zv)));
      yf[r * D_INNER + d] = yv;
    }
  }
}

// ---------------------- pool phase 1: partial sums over 14-token chunks -----
__global__ __launch_bounds__(128) void k_pool1(const float* __restrict__ tl,
                                               float* __restrict__ partial) {
  const int b = blockIdx.x, g = blockIdx.y, tid = threadIdx.x;
  float m[3] = {0.f, 0.f, 0.f};
  for (int l = g * 14; l < (g + 1) * 14; l++) {
    size_t row = ((size_t)b * LTOK + l) * D_MODEL;
#pragma unroll
    for (int j = 0; j < 3; j++) m[j] += tl[row + tid + j * 128];
  }
#pragma unroll
  for (int j = 0; j < 3; j++)
    partial[((size_t)b * 14 + g) * D_MODEL + tid + j * 128] = m[j];
}

// ------------------ pool phase 2: finalize mean + expmap0 -------------------
__global__ __launch_bounds__(128) void k_pool2(const float* __restrict__ partial,
                                               float* __restrict__ pooled,
                                               float* __restrict__ x2v) {
  __shared__ float sm[2];
  const int b = blockIdx.x, tid = threadIdx.x;
  float m[3] = {0.f, 0.f, 0.f};
  for (int g = 0; g < 14; g++) {
    size_t row = ((size_t)b * 14 + g) * D_MODEL;
#pragma unroll
    for (int j = 0; j < 3; j++) m[j] += partial[row + tid + j * 128];
  }
#pragma unroll
  for (int j = 0; j < 3; j++) m[j] *= (1.f / (float)LTOK);
  float s = blockSum128(m[0] * m[0] + m[1] * m[1] + m[2] * m[2], sm);
  float n = sqrtf(s + 1e-15f);
  float nc = clampf(n, 1e-8f, 5.f);
  float ke = tanhf(kSqrtC * nc) / (kSqrtC * nc);
  float rn = sqrtf(ke * ke * s + 1e-15f);
  float sc = rn > kMaxNorm ? kMaxNorm / rn : 1.f;
  float kk = ke * sc;
  float p[3];
#pragma unroll
  for (int j = 0; j < 3; j++) {
    p[j] = kk * m[j];
    pooled[(size_t)b * D_MODEL + tid + j * 128] = p[j];
  }
  float s2 = blockSum128(p[0] * p[0] + p[1] * p[1] + p[2] * p[2], sm);
  if (tid == 0) x2v[b] = s2;
}

// ------------------- hyperbolic distance head over prototypes ---------------
__global__ __launch_bounds__(256) void k_head(const float* __restrict__ pooled,
                                              const float* __restrict__ protos,
                                              const float* __restrict__ x2v,
                                              float* __restrict__ out) {
  __shared__ float sp[D_MODEL];
  const int b = blockIdx.y;
  const int c = blockIdx.x * 256 + threadIdx.x;
  for (int j = threadIdx.x; j < D_MODEL; j += 256)
    sp[j] = pooled[(size_t)b * D_MODEL + j];
  __syncthreads();
  if (c >= NCLS) return;
  const float* pr = protos + (size_t)c * D_MODEL;
  float dotv = 0.f, y2 = 0.f;
  for (int k = 0; k < D_MODEL; k++) {
    float w = pr[k];
    dotv += sp[k] * w;
    y2 += w * w;
  }
  float x2 = x2v[b];
  float xy = -dotv;                       // <a,b>, a = -pooled
  float al = 1.f + xy + 0.5f * y2;        // 1 + 2c*xy + c*y2
  float be = 1.f - 0.5f * x2;
  float num2 = al * al * x2 + 2.f * al * be * xy + be * be * y2;
  float den = fmaxf(1.f + xy + 0.25f * x2 * y2, 1e-15f);
  float r2 = num2 / (den * den) + 1e-15f;
  float dn = fminf(kSqrtC * sqrtf(r2), 1.f - 1e-5f);
  out[(size_t)b * NCLS + c] = -(2.f / kSqrtC) * atanhf(dn);
}

// ---------------------------------------------------------------------------
extern "C" void kernel_launch(void* const* d_in, const int* in_sizes, int n_in,
                              void* d_out, int out_size, void* d_ws,
                              size_t ws_size, hipStream_t stream) {
  const float* x        = (const float*)d_in[0];
  const float* patch_w  = (const float*)d_in[1];
  const float* patch_b  = (const float*)d_in[2];
  const float* hyp_w    = (const float*)d_in[3];
  const float* hyp_b    = (const float*)d_in[4];
  const float* pe_gamma = (const float*)d_in[5];
  const float* pe_beta  = (const float*)d_in[6];
  const float* pos      = (const float*)d_in[7];
  const float* in_w     = (const float*)d_in[8];
  const float* conv_w   = (const float*)d_in[9];
  const float* conv_b   = (const float*)d_in[10];
  const float* xp_w     = (const float*)d_in[11];
  const float* dt_w     = (const float*)d_in[12];
  const float* dt_bias  = (const float*)d_in[13];
  const float* A_log    = (const float*)d_in[14];
  const float* Dp       = (const float*)d_in[15];
  const float* out_w    = (const float*)d_in[16];
  const float* gamma    = (const float*)d_in[17];
  const float* beta     = (const float*)d_in[18];
  const float* gamma_f  = (const float*)d_in[19];
  const float* beta_f   = (const float*)d_in[20];
  const float* protos   = (const float*)d_in[21];
  float* out = (float*)d_out;

  // workspace layout (floats); ~63.8 MB total
  float* base    = (float*)d_ws;
  float* hidden  = base;
  float* resid   = hidden  + (size_t)NROW * D_MODEL;
  float* hn      = resid   + (size_t)NROW * D_MODEL;
  float* xz      = hn      + (size_t)NROW * D_MODEL;
  float* u       = xz      + (size_t)NROW * 2 * D_INNER;
  float* dtbuf   = u       + (size_t)NROW * D_INNER;
  float* yf      = dtbuf   + (size_t)NROW * D_INNER;
  float* dbl     = yf      + (size_t)NROW * D_INNER;
  float* xn      = dbl     + (size_t)NROW * NXP;
  float* pooled  = xn      + NROW;
  float* x2v     = pooled  + (size_t)BSZ * D_MODEL;
  float* partial = x2v     + BSZ;                       // 16*14*384
  // stem-phase aliases (dead regions during stem)
  float* P      = xz;     // 3136 x 768 im2col
  float* tokens = u;      // 3136 x 384
  float* mx     = dtbuf;  // 3136 x 384

  // stem
  k_im2col<<<dim3((NROW * 768) / 256), dim3(256), 0, stream>>>(x, P);
  k_gemm_bf16<<<dim3(NROW / 64, D_MODEL / 64), dim3(256), 0, stream>>>(
      P, patch_w, patch_b, tokens, NROW, D_MODEL, 768);
  k_stem_a<<<dim3(NROW), dim3(128), 0, stream>>>(tokens, hidden, xn);
  k_gemm_bf16<<<dim3(NROW / 64, D_MODEL / 64), dim3(256), 0, stream>>>(
      hidden, hyp_w, nullptr, mx, NROW, D_MODEL, D_MODEL);
  k_stem_b<<<dim3(NROW), dim3(128), 0, stream>>>(mx, xn, hyp_b, pe_gamma,
                                                 pe_beta, pos, hidden);
  // layers
  for (int i = 0; i < NDEPTH; i++) {
    k_resln<<<dim3(NROW), dim3(128), 0, stream>>>(
        hidden, resid, resid, gamma + (size_t)i * D_MODEL,
        beta + (size_t)i * D_MODEL, hn, i == 0 ? 1 : 0, 0);
    k_gemm_bf16<<<dim3(NROW / 64, (2 * D_INNER) / 64), dim3(256), 0, stream>>>(
        hn, in_w + (size_t)i * 2 * D_INNER * D_MODEL, nullptr, xz, NROW,
        2 * D_INNER, D_MODEL);
    k_convx<<<dim3(NROW), dim3(256), 0, stream>>>(
        xz, conv_w + (size_t)i * D_INNER * 4, conv_b + (size_t)i * D_INNER,
        xp_w + (size_t)i * NXP * D_INNER,
        dt_w + (size_t)i * D_INNER * DT_RANK, dt_bias + (size_t)i * D_INNER,
        u, dbl, dtbuf);
    k_scan<<<dim3(D_INNER / 16, BSZ), dim3(256), 0, stream>>>(
        u, dtbuf, dbl, xz, A_log + (size_t)i * D_INNER * D_STATE,
        Dp + (size_t)i * D_INNER, yf);
    k_gemm_bf16<<<dim3(NROW / 64, D_MODEL / 64), dim3(256), 0, stream>>>(
        yf, out_w + (size_t)i * D_MODEL * D_INNER, nullptr, hidden, NROW,
        D_MODEL, D_INNER);
  }
  // head
  k_resln<<<dim3(NROW), dim3(128), 0, stream>>>(hidden, resid, resid, gamma_f,
                                                beta_f, hn, 0, 1);
  k_pool1<<<dim3(BSZ, 14), dim3(128), 0, stream>>>(hn, partial);
  k_pool2<<<dim3(BSZ), dim3(128), 0, stream>>>(partial, pooled, x2v);
  k_head<<<dim3((NCLS + 255) / 256, BSZ), dim3(256), 0, stream>>>(pooled,
                                                                  protos, x2v,
                                                                  out);
}

// Round 3
// 4140.630 us; speedup vs baseline: 2.1951x; 1.8285x over previous
//
#include <hip/hip_runtime.h>
#include <hip/hip_bf16.h>
#include <math.h>

#define D_MODEL 384
#define D_INNER 768
#define D_STATE 16
#define DT_RANK 24
#define NXP 56          // DT_RANK + 2*D_STATE
#define LTOK 196
#define BSZ 16
#define NROW 3136       // BSZ * LTOK
#define NDEPTH 24
#define NCLS 1000

constexpr float kSqrtC   = 0.70710678118654752440f;
constexpr float kMaxNorm = 0.95f / 0.70710678118654752440f;   // 1.3435029...

typedef short  bf16x8 __attribute__((ext_vector_type(8)));
typedef float  f32x4  __attribute__((ext_vector_type(4)));

__device__ __forceinline__ float clampf(float x, float lo, float hi) {
  return fminf(fmaxf(x, lo), hi);
}

// f32 -> bf16 (RNE) as raw short
__device__ __forceinline__ short f2bf(float f) {
  union { float f; unsigned u; } v; v.f = f;
  unsigned r = (v.u + 0x7FFFu + ((v.u >> 16) & 1u)) >> 16;
  return (short)r;
}

// 64-lane wave reduction (no LDS, no barriers)
__device__ __forceinline__ float waveSum(float v) {
#pragma unroll
  for (int o = 1; o < 64; o <<= 1) v += __shfl_xor(v, o, 64);
  return v;
}

// block=128 sum-reduce with broadcast (stem kernels only).
__device__ __forceinline__ float blockSum128(float v, float* sm) {
#pragma unroll
  for (int o = 32; o > 0; o >>= 1) v += __shfl_down(v, o, 64);
  __syncthreads();
  if ((threadIdx.x & 63) == 0) sm[threadIdx.x >> 6] = v;
  __syncthreads();
  return sm[0] + sm[1];
}

// ---------------------------------------------------------------- im2col ----
__global__ __launch_bounds__(256) void k_im2col(const float* __restrict__ x,
                                                float* __restrict__ P) {
  size_t idx = (size_t)blockIdx.x * 256 + threadIdx.x;
  if (idx >= (size_t)NROW * 768) return;
  int k = (int)(idx % 768);
  int r = (int)(idx / 768);
  int b = r / LTOK, t = r % LTOK;
  int hp = t / 14, wp = t % 14;
  int c = k / 256, rem = k % 256, i = rem / 16, j = rem % 16;
  P[idx] = x[(((size_t)(b * 3 + c) * 224) + hp * 16 + i) * 224 + wp * 16 + j];
}

// --------------------------------------- bf16 MFMA GEMM: C = A * W^T (+b) ---
// A (M,K) f32 rm row-stride lda, W (Nv,K) f32 rm row-stride K, C row-stride
// ldc. Grid (M/64, Npad/64). Guards: W rows >= Nv staged as 0, stores cg<Nv,
// K tail (K%32!=0) zero-padded. act: 0 none, 1 softplus, 2 silu if cg>=768.
#define LDA 40
__global__ __launch_bounds__(256) void k_gemm_bf16(
    const float* __restrict__ A, const float* __restrict__ W,
    const float* __restrict__ bias, float* __restrict__ Cm,
    int K, int lda, int ldc, int Nv, int act) {
  __shared__ short As[64 * LDA];
  __shared__ short Ws[64 * LDA];
  const int tid = threadIdx.x;
  const int m0 = blockIdx.x * 64;
  const int n0 = blockIdx.y * 64;
  const int lane = tid & 63;
  const int wave = tid >> 6;
  const int wm = wave & 1, wn = wave >> 1;
  const int lm = lane & 15;
  const int quad = lane >> 4;
  const int srow = tid >> 2;
  const int sseg = tid & 3;

  f32x4 acc[2][2];
#pragma unroll
  for (int i = 0; i < 2; i++)
#pragma unroll
    for (int j = 0; j < 2; j++) acc[i][j] = (f32x4){0.f, 0.f, 0.f, 0.f};

  const float* rowA = A + (size_t)(m0 + srow) * lda;
  const int wrow = n0 + srow;
  const float* rowW = W + (size_t)wrow * K;
  const bool wvalid = wrow < Nv;

  for (int k0 = 0; k0 < K; k0 += 32) {
    short sa[8], sw[8];
    if (k0 + 32 <= K) {
      float4 a0 = *(const float4*)(rowA + k0 + sseg * 8);
      float4 a1 = *(const float4*)(rowA + k0 + sseg * 8 + 4);
      float4 w0 = {0.f, 0.f, 0.f, 0.f}, w1 = {0.f, 0.f, 0.f, 0.f};
      if (wvalid) {
        w0 = *(const float4*)(rowW + k0 + sseg * 8);
        w1 = *(const float4*)(rowW + k0 + sseg * 8 + 4);
      }
      sa[0] = f2bf(a0.x); sa[1] = f2bf(a0.y); sa[2] = f2bf(a0.z); sa[3] = f2bf(a0.w);
      sa[4] = f2bf(a1.x); sa[5] = f2bf(a1.y); sa[6] = f2bf(a1.z); sa[7] = f2bf(a1.w);
      sw[0] = f2bf(w0.x); sw[1] = f2bf(w0.y); sw[2] = f2bf(w0.z); sw[3] = f2bf(w0.w);
      sw[4] = f2bf(w1.x); sw[5] = f2bf(w1.y); sw[6] = f2bf(w1.z); sw[7] = f2bf(w1.w);
    } else {
#pragma unroll
      for (int kk = 0; kk < 8; kk++) {
        int k = k0 + sseg * 8 + kk;
        float av = (k < K) ? rowA[k] : 0.f;
        float wv = (wvalid && k < K) ? rowW[k] : 0.f;
        sa[kk] = f2bf(av); sw[kk] = f2bf(wv);
      }
    }
    __syncthreads();  // guard LDS reuse from previous iter's reads
    *(short4*)&As[srow * LDA + sseg * 8]     = (short4){sa[0], sa[1], sa[2], sa[3]};
    *(short4*)&As[srow * LDA + sseg * 8 + 4] = (short4){sa[4], sa[5], sa[6], sa[7]};
    *(short4*)&Ws[srow * LDA + sseg * 8]     = (short4){sw[0], sw[1], sw[2], sw[3]};
    *(short4*)&Ws[srow * LDA + sseg * 8 + 4] = (short4){sw[4], sw[5], sw[6], sw[7]};
    __syncthreads();
    bf16x8 af[2], bf[2];
#pragma unroll
    for (int i = 0; i < 2; i++) {
      af[i] = *(bf16x8*)&As[(wm * 32 + i * 16 + lm) * LDA + quad * 8];
      bf[i] = *(bf16x8*)&Ws[(wn * 32 + i * 16 + lm) * LDA + quad * 8];
    }
#pragma unroll
    for (int i = 0; i < 2; i++)
#pragma unroll
      for (int j = 0; j < 2; j++)
        acc[i][j] = __builtin_amdgcn_mfma_f32_16x16x32_bf16(af[i], bf[j],
                                                            acc[i][j], 0, 0, 0);
  }
  // epilogue: C/D layout col=lane&15, row=quad*4+reg
#pragma unroll
  for (int i = 0; i < 2; i++) {
#pragma unroll
    for (int j = 0; j < 2; j++) {
      int cg = n0 + wn * 32 + j * 16 + lm;
      if (cg >= Nv) continue;
      float bj = bias ? bias[cg] : 0.f;
#pragma unroll
      for (int reg = 0; reg < 4; reg++) {
        int rg = m0 + wm * 32 + i * 16 + quad * 4 + reg;
        float o = acc[i][j][reg] + bj;
        if (act == 1) o = (o > 20.f) ? o : log1pf(expf(o));
        else if (act == 2 && cg >= 768) o = o / (1.f + expf(-o));
        Cm[(size_t)rg * ldc + cg] = o;
      }
    }
  }
}

// --------------------------------------------- stem a: expmap0(tokens) ------
__global__ __launch_bounds__(128) void k_stem_a(const float* __restrict__ tok,
                                                float* __restrict__ h,
                                                float* __restrict__ xn) {
  __shared__ float sm[2];
  const int r = blockIdx.x, tid = threadIdx.x;
  float v[3];
#pragma unroll
  for (int j = 0; j < 3; j++) v[j] = tok[(size_t)r * D_MODEL + tid + j * 128];
  float s = blockSum128(v[0] * v[0] + v[1] * v[1] + v[2] * v[2], sm);
  float n = sqrtf(s + 1e-15f);
  float nc = clampf(n, 1e-8f, 5.f);
  float ke = tanhf(kSqrtC * nc) / (kSqrtC * nc);
  float rn = sqrtf(ke * ke * s + 1e-15f);
  float sc = rn > kMaxNorm ? kMaxNorm / rn : 1.f;
  float kk = ke * sc;
#pragma unroll
  for (int j = 0; j < 3; j++) h[(size_t)r * D_MODEL + tid + j * 128] = kk * v[j];
  if (tid == 0) xn[r] = fmaxf(sqrtf(kk * kk * s + 1e-15f), 1e-8f);
}

// --- stem b: mobius_matvec tail + mobius_add(hyp_b) + hyp_LN + pos + expmap -
__global__ __launch_bounds__(128) void k_stem_b(
    const float* __restrict__ mx, const float* __restrict__ xn,
    const float* __restrict__ hyp_b, const float* __restrict__ pe_g,
    const float* __restrict__ pe_b, const float* __restrict__ pos,
    float* __restrict__ outh) {
  __shared__ float sm[2];
  const int r = blockIdx.x, tid = threadIdx.x;
  const int t = r % LTOK;
  float mv[3], bv[3];
  int dd[3];
#pragma unroll
  for (int j = 0; j < 3; j++) {
    dd[j] = tid + j * 128;
    mv[j] = mx[(size_t)r * D_MODEL + dd[j]];
    bv[j] = hyp_b[dd[j]];
  }
  float smx = blockSum128(mv[0] * mv[0] + mv[1] * mv[1] + mv[2] * mv[2], sm);
  float mxn = fmaxf(sqrtf(smx + 1e-15f), 1e-8f);
  float xnv = xn[r];
  float tt = tanhf(mxn / xnv * atanhf(fminf(kSqrtC * xnv, 1.f - 1e-5f)));
  float kres = tt / (mxn * kSqrtC);
  float res[3];
#pragma unroll
  for (int j = 0; j < 3; j++) res[j] = kres * mv[j];
  float xy = blockSum128(res[0] * bv[0] + res[1] * bv[1] + res[2] * bv[2], sm);
  float y2 = blockSum128(bv[0] * bv[0] + bv[1] * bv[1] + bv[2] * bv[2], sm);
  float x2 = kres * kres * smx;
  float al = 1.f + xy + 0.5f * y2;
  float be = 1.f - 0.5f * x2;
  float den = fmaxf(1.f + xy + 0.25f * x2 * y2, 1e-15f);
  float h1[3];
#pragma unroll
  for (int j = 0; j < 3; j++) h1[j] = (al * res[j] + be * bv[j]) / den;
  float s1 = blockSum128(h1[0] * h1[0] + h1[1] * h1[1] + h1[2] * h1[2], sm);
  float n1 = sqrtf(s1 + 1e-15f);
  float nc1 = clampf(n1, 1e-8f, kMaxNorm);
  float kl = atanhf(fminf(kSqrtC * nc1, 0.95f)) / (kSqrtC * nc1);
  float tl[3];
#pragma unroll
  for (int j = 0; j < 3; j++) tl[j] = kl * h1[j];
  float mean = blockSum128(tl[0] + tl[1] + tl[2], sm) * (1.f / 384.f);
  float dv = 0.f;
#pragma unroll
  for (int j = 0; j < 3; j++) { float d = tl[j] - mean; dv += d * d; }
  float var = blockSum128(dv, sm) * (1.f / 383.f);
  float inv = 1.f / (sqrtf(var) + 1e-5f);
  float g[3];
#pragma unroll
  for (int j = 0; j < 3; j++)
    g[j] = (tl[j] - mean) * inv * pe_g[dd[j]] + pe_b[dd[j]];
  float sg = blockSum128(g[0] * g[0] + g[1] * g[1] + g[2] * g[2], sm);
  float ng = sqrtf(sg + 1e-15f);
  float nc2 = clampf(ng, 1e-8f, 5.f);
  float ke = tanhf(kSqrtC * nc2) / (kSqrtC * nc2);
  float rn = sqrtf(ke * ke * sg + 1e-15f);
  float sc = rn > kMaxNorm ? kMaxNorm / rn : 1.f;
  float kk = ke * sc;
  float s2 = kk * kk * sg;
  float n3 = sqrtf(s2 + 1e-15f);
  float nc3 = clampf(n3, 1e-8f, kMaxNorm);
  float kl2 = atanhf(fminf(kSqrtC * nc3, 0.95f)) / (kSqrtC * nc3);
  float v[3];
#pragma unroll
  for (int j = 0; j < 3; j++)
    v[j] = kl2 * kk * g[j] + pos[(size_t)t * D_MODEL + dd[j]];
  float sv = blockSum128(v[0] * v[0] + v[1] * v[1] + v[2] * v[2], sm);
  float nv = sqrtf(sv + 1e-15f);
  float nc4 = clampf(nv, 1e-8f, 5.f);
  float ke2 = tanhf(kSqrtC * nc4) / (kSqrtC * nc4);
  float rn2 = sqrtf(ke2 * ke2 * sv + 1e-15f);
  float sc2 = rn2 > kMaxNorm ? kMaxNorm / rn2 : 1.f;
#pragma unroll
  for (int j = 0; j < 3; j++)
    outh[(size_t)r * D_MODEL + dd[j]] = ke2 * sc2 * v[j];
}

// --- residual accumulate + hyp_layernorm, one wave per row (no barriers) ----
__global__ __launch_bounds__(256) void k_resln(
    const float* __restrict__ hid, const float* __restrict__ res_in,
    float* __restrict__ res_out, const float* __restrict__ g_,
    const float* __restrict__ b_, float* __restrict__ outp, int first,
    int out_logmap) {
  const int lane = threadIdx.x & 63;
  const int r = blockIdx.x * 4 + (threadIdx.x >> 6);
  float v[6];
  int dd[6];
#pragma unroll
  for (int j = 0; j < 6; j++) {
    dd[j] = lane + j * 64;
    size_t idx = (size_t)r * D_MODEL + dd[j];
    v[j] = hid[idx] + (first ? 0.f : res_in[idx]);
    res_out[idx] = v[j];
  }
  float ss = 0.f;
#pragma unroll
  for (int j = 0; j < 6; j++) ss += v[j] * v[j];
  float s = waveSum(ss);
  float n = sqrtf(s + 1e-15f);
  float nc = clampf(n, 1e-8f, kMaxNorm);
  float kl = atanhf(fminf(kSqrtC * nc, 0.95f)) / (kSqrtC * nc);
  float t[6];
  float ts = 0.f;
#pragma unroll
  for (int j = 0; j < 6; j++) { t[j] = kl * v[j]; ts += t[j]; }
  float mean = waveSum(ts) * (1.f / 384.f);
  float dv = 0.f;
#pragma unroll
  for (int j = 0; j < 6; j++) { float d = t[j] - mean; dv += d * d; }
  float var = waveSum(dv) * (1.f / 383.f);
  float inv = 1.f / (sqrtf(var) + 1e-5f);
  float g[6];
  float gs = 0.f;
#pragma unroll
  for (int j = 0; j < 6; j++) {
    g[j] = (t[j] - mean) * inv * g_[dd[j]] + b_[dd[j]];
    gs += g[j] * g[j];
  }
  float sg = waveSum(gs);
  float ng = sqrtf(sg + 1e-15f);
  float nc2 = clampf(ng, 1e-8f, 5.f);
  float ke = tanhf(kSqrtC * nc2) / (kSqrtC * nc2);
  float rn = sqrtf(ke * ke * sg + 1e-15f);
  float sc = rn > kMaxNorm ? kMaxNorm / rn : 1.f;
  float kk = ke * sc;
  if (!out_logmap) {
#pragma unroll
    for (int j = 0; j < 6; j++) outp[(size_t)r * D_MODEL + dd[j]] = kk * g[j];
  } else {
    float s2 = kk * kk * sg;
    float n3 = sqrtf(s2 + 1e-15f);
    float nc3 = clampf(n3, 1e-8f, kMaxNorm);
    float kl2 = atanhf(fminf(kSqrtC * nc3, 0.95f)) / (kSqrtC * nc3);
#pragma unroll
    for (int j = 0; j < 6; j++)
      outp[(size_t)r * D_MODEL + dd[j]] = kl2 * kk * g[j];
  }
}

// --------------------- conv1d(k=4, causal) + SiLU, float4 over d ------------
__global__ __launch_bounds__(256) void k_conv(const float* __restrict__ xz,
                                              const float* __restrict__ cw,
                                              const float* __restrict__ cb,
                                              float* __restrict__ u) {
  int idx = blockIdx.x * 256 + threadIdx.x;   // NROW*192 total
  if (idx >= NROW * 192) return;
  int d4 = idx % 192, r = idx / 192;
  int b = r / LTOK, l = r % LTOK;
  float4 acc = *(const float4*)(cb + d4 * 4);
  float4 c0 = *(const float4*)(cw + (d4 * 4 + 0) * 4);
  float4 c1 = *(const float4*)(cw + (d4 * 4 + 1) * 4);
  float4 c2 = *(const float4*)(cw + (d4 * 4 + 2) * 4);
  float4 c3 = *(const float4*)(cw + (d4 * 4 + 3) * 4);
  const float* cc0 = (const float*)&c0;
  const float* cc1 = (const float*)&c1;
  const float* cc2 = (const float*)&c2;
  const float* cc3 = (const float*)&c3;
#pragma unroll
  for (int k = 0; k < 4; k++) {
    int ll = l - 3 + k;
    if (ll >= 0) {
      float4 xv = *(const float4*)(xz + (size_t)(b * LTOK + ll) * (2 * D_INNER) + d4 * 4);
      acc.x = fmaf(cc0[k], xv.x, acc.x);
      acc.y = fmaf(cc1[k], xv.y, acc.y);
      acc.z = fmaf(cc2[k], xv.z, acc.z);
      acc.w = fmaf(cc3[k], xv.w, acc.w);
    }
  }
  float4 o;
  o.x = acc.x / (1.f + expf(-acc.x));
  o.y = acc.y / (1.f + expf(-acc.y));
  o.z = acc.z / (1.f + expf(-acc.z));
  o.w = acc.w / (1.f + expf(-acc.w));
  *(float4*)(u + (size_t)r * D_INNER + d4 * 4) = o;
}

// ------ selective scan, (b,d,n)-parallel, chunked double-buffered prefetch --
#define SCH 7
#define NCH 28   // 28*7 = 196
#define LOADC(dtA, uA, BA, CA, zA, c)                                   \
  do {                                                                  \
    _Pragma("unroll") for (int j = 0; j < SCH; j++) {                   \
      size_t r = base + (size_t)(c) * SCH + j;                          \
      dtA[j] = dtbuf[r * D_INNER + d];                                  \
      uA[j]  = u[r * D_INNER + d];                                      \
      BA[j]  = dbl[r * NXP + DT_RANK + n];                              \
      CA[j]  = dbl[r * NXP + DT_RANK + D_STATE + n];                    \
      zA[j]  = xz[r * (2 * D_INNER) + D_INNER + d];                     \
    }                                                                   \
  } while (0)
#define COMPC(dtA, uA, BA, CA, zA, c)                                   \
  do {                                                                  \
    float dA[SCH], bu[SCH];                                             \
    _Pragma("unroll") for (int j = 0; j < SCH; j++) {                   \
      dA[j] = expf(dtA[j] * a);                                         \
      bu[j] = dtA[j] * BA[j] * uA[j];                                   \
    }                                                                   \
    _Pragma("unroll") for (int j = 0; j < SCH; j++) {                   \
      h = fmaf(dA[j], h, bu[j]);                                        \
      float y = h * CA[j];                                              \
      y += __shfl_xor(y, 1, 64);                                        \
      y += __shfl_xor(y, 2, 64);                                        \
      y += __shfl_xor(y, 4, 64);                                        \
      y += __shfl_xor(y, 8, 64);                                        \
      if (n == 0) {                                                     \
        size_t r = base + (size_t)(c) * SCH + j;                        \
        yf[r * D_INNER + d] = fmaf(Dv, uA[j], y) * zA[j];               \
      }                                                                 \
    }                                                                   \
  } while (0)

__global__ __launch_bounds__(256, 3) void k_scan(
    const float* __restrict__ u, const float* __restrict__ dtbuf,
    const float* __restrict__ dbl, const float* __restrict__ xz,
    const float* __restrict__ A_log, const float* __restrict__ Dp,
    float* __restrict__ yf) {
  const int tid = threadIdx.x;
  const int n = tid & 15, dl = tid >> 4;
  const int d = blockIdx.x * 16 + dl;
  const int b = blockIdx.y;
  const float a = -expf(A_log[(size_t)d * D_STATE + n]);
  const float Dv = Dp[d];
  const size_t base = (size_t)b * LTOK;
  float h = 0.f;
  float dt0[SCH], u0[SCH], B0[SCH], C0[SCH], z0[SCH];
  float dt1[SCH], u1[SCH], B1[SCH], C1[SCH], z1[SCH];
  LOADC(dt0, u0, B0, C0, z0, 0);
  for (int c = 0; c < NCH; c += 2) {
    LOADC(dt1, u1, B1, C1, z1, c + 1);
    COMPC(dt0, u0, B0, C0, z0, c);
    if (c + 2 < NCH) LOADC(dt0, u0, B0, C0, z0, c + 2);
    COMPC(dt1, u1, B1, C1, z1, c + 1);
  }
}

// ---------------------- pool phase 1: partial sums over 14-token chunks -----
__global__ __launch_bounds__(128) void k_pool1(const float* __restrict__ tl,
                                               float* __restrict__ partial) {
  const int b = blockIdx.x, g = blockIdx.y, tid = threadIdx.x;
  float m[3] = {0.f, 0.f, 0.f};
  for (int l = g * 14; l < (g + 1) * 14; l++) {
    size_t row = ((size_t)b * LTOK + l) * D_MODEL;
#pragma unroll
    for (int j = 0; j < 3; j++) m[j] += tl[row + tid + j * 128];
  }
#pragma unroll
  for (int j = 0; j < 3; j++)
    partial[((size_t)b * 14 + g) * D_MODEL + tid + j * 128] = m[j];
}

// ------------------ pool phase 2: finalize mean + expmap0 -------------------
__global__ __launch_bounds__(128) void k_pool2(const float* __restrict__ partial,
                                               float* __restrict__ pooled,
                                               float* __restrict__ x2v) {
  __shared__ float sm[2];
  const int b = blockIdx.x, tid = threadIdx.x;
  float m[3] = {0.f, 0.f, 0.f};
  for (int g = 0; g < 14; g++) {
    size_t row = ((size_t)b * 14 + g) * D_MODEL;
#pragma unroll
    for (int j = 0; j < 3; j++) m[j] += partial[row + tid + j * 128];
  }
#pragma unroll
  for (int j = 0; j < 3; j++) m[j] *= (1.f / (float)LTOK);
  float s = blockSum128(m[0] * m[0] + m[1] * m[1] + m[2] * m[2], sm);
  float n = sqrtf(s + 1e-15f);
  float nc = clampf(n, 1e-8f, 5.f);
  float ke = tanhf(kSqrtC * nc) / (kSqrtC * nc);
  float rn = sqrtf(ke * ke * s + 1e-15f);
  float sc = rn > kMaxNorm ? kMaxNorm / rn : 1.f;
  float kk = ke * sc;
  float p[3];
#pragma unroll
  for (int j = 0; j < 3; j++) {
    p[j] = kk * m[j];
    pooled[(size_t)b * D_MODEL + tid + j * 128] = p[j];
  }
  float s2 = blockSum128(p[0] * p[0] + p[1] * p[1] + p[2] * p[2], sm);
  if (tid == 0) x2v[b] = s2;
}

// ------------------- hyperbolic distance head over prototypes ---------------
__global__ __launch_bounds__(256) void k_head(const float* __restrict__ pooled,
                                              const float* __restrict__ protos,
                                              const float* __restrict__ x2v,
                                              float* __restrict__ out) {
  __shared__ float sp[D_MODEL];
  const int b = blockIdx.y;
  const int c = blockIdx.x * 256 + threadIdx.x;
  for (int j = threadIdx.x; j < D_MODEL; j += 256)
    sp[j] = pooled[(size_t)b * D_MODEL + j];
  __syncthreads();
  if (c >= NCLS) return;
  const float* pr = protos + (size_t)c * D_MODEL;
  float dotv = 0.f, y2 = 0.f;
  for (int k = 0; k < D_MODEL; k++) {
    float w = pr[k];
    dotv += sp[k] * w;
    y2 += w * w;
  }
  float x2 = x2v[b];
  float xy = -dotv;
  float al = 1.f + xy + 0.5f * y2;
  float be = 1.f - 0.5f * x2;
  float num2 = al * al * x2 + 2.f * al * be * xy + be * be * y2;
  float den = fmaxf(1.f + xy + 0.25f * x2 * y2, 1e-15f);
  float r2 = num2 / (den * den) + 1e-15f;
  float dn = fminf(kSqrtC * sqrtf(r2), 1.f - 1e-5f);
  out[(size_t)b * NCLS + c] = -(2.f / kSqrtC) * atanhf(dn);
}

// ---------------------------------------------------------------------------
extern "C" void kernel_launch(void* const* d_in, const int* in_sizes, int n_in,
                              void* d_out, int out_size, void* d_ws,
                              size_t ws_size, hipStream_t stream) {
  const float* x        = (const float*)d_in[0];
  const float* patch_w  = (const float*)d_in[1];
  const float* patch_b  = (const float*)d_in[2];
  const float* hyp_w    = (const float*)d_in[3];
  const float* hyp_b    = (const float*)d_in[4];
  const float* pe_gamma = (const float*)d_in[5];
  const float* pe_beta  = (const float*)d_in[6];
  const float* pos      = (const float*)d_in[7];
  const float* in_w     = (const float*)d_in[8];
  const float* conv_w   = (const float*)d_in[9];
  const float* conv_b   = (const float*)d_in[10];
  const float* xp_w     = (const float*)d_in[11];
  const float* dt_w     = (const float*)d_in[12];
  const float* dt_bias  = (const float*)d_in[13];
  const float* A_log    = (const float*)d_in[14];
  const float* Dp       = (const float*)d_in[15];
  const float* out_w    = (const float*)d_in[16];
  const float* gamma    = (const float*)d_in[17];
  const float* beta     = (const float*)d_in[18];
  const float* gamma_f  = (const float*)d_in[19];
  const float* beta_f   = (const float*)d_in[20];
  const float* protos   = (const float*)d_in[21];
  float* out = (float*)d_out;

  float* base    = (float*)d_ws;
  float* hidden  = base;
  float* resid   = hidden  + (size_t)NROW * D_MODEL;
  float* hn      = resid   + (size_t)NROW * D_MODEL;
  float* xz      = hn      + (size_t)NROW * D_MODEL;
  float* u       = xz      + (size_t)NROW * 2 * D_INNER;
  float* dtbuf   = u       + (size_t)NROW * D_INNER;
  float* yf      = dtbuf   + (size_t)NROW * D_INNER;
  float* dbl     = yf      + (size_t)NROW * D_INNER;
  float* xn      = dbl     + (size_t)NROW * NXP;
  float* pooled  = xn      + NROW;
  float* x2v     = pooled  + (size_t)BSZ * D_MODEL;
  float* partial = x2v     + BSZ;                       // 16*14*384
  // stem-phase aliases (dead regions during stem)
  float* P      = xz;     // 3136 x 768 im2col
  float* tokens = u;      // 3136 x 384
  float* mx     = dtbuf;  // 3136 x 384

  // stem
  k_im2col<<<dim3((NROW * 768) / 256), dim3(256), 0, stream>>>(x, P);
  k_gemm_bf16<<<dim3(NROW / 64, 6), dim3(256), 0, stream>>>(
      P, patch_w, patch_b, tokens, 768, 768, D_MODEL, D_MODEL, 0);
  k_stem_a<<<dim3(NROW), dim3(128), 0, stream>>>(tokens, hidden, xn);
  k_gemm_bf16<<<dim3(NROW / 64, 6), dim3(256), 0, stream>>>(
      hidden, hyp_w, nullptr, mx, D_MODEL, D_MODEL, D_MODEL, D_MODEL, 0);
  k_stem_b<<<dim3(NROW), dim3(128), 0, stream>>>(mx, xn, hyp_b, pe_gamma,
                                                 pe_beta, pos, hidden);
  // layers
  for (int i = 0; i < NDEPTH; i++) {
    k_resln<<<dim3(NROW / 4), dim3(256), 0, stream>>>(
        hidden, resid, resid, gamma + (size_t)i * D_MODEL,
        beta + (size_t)i * D_MODEL, hn, i == 0 ? 1 : 0, 0);
    // in_proj (z-half gets SiLU fused: act=2)
    k_gemm_bf16<<<dim3(NROW / 64, 24), dim3(256), 0, stream>>>(
        hn, in_w + (size_t)i * 2 * D_INNER * D_MODEL, nullptr, xz, D_MODEL,
        D_MODEL, 2 * D_INNER, 2 * D_INNER, 2);
    k_conv<<<dim3((NROW * 192 + 255) / 256), dim3(256), 0, stream>>>(
        xz, conv_w + (size_t)i * D_INNER * 4, conv_b + (size_t)i * D_INNER, u);
    // x_proj: N 56 padded to 64
    k_gemm_bf16<<<dim3(NROW / 64, 1), dim3(256), 0, stream>>>(
        u, xp_w + (size_t)i * NXP * D_INNER, nullptr, dbl, D_INNER, D_INNER,
        NXP, NXP, 0);
    // dt_proj: K=24 (zero-padded to 32), softplus+bias epilogue
    k_gemm_bf16<<<dim3(NROW / 64, 12), dim3(256), 0, stream>>>(
        dbl, dt_w + (size_t)i * D_INNER * DT_RANK, dt_bias + (size_t)i * D_INNER,
        dtbuf, DT_RANK, NXP, D_INNER, D_INNER, 1);
    k_scan<<<dim3(D_INNER / 16, BSZ), dim3(256), 0, stream>>>(
        u, dtbuf, dbl, xz, A_log + (size_t)i * D_INNER * D_STATE,
        Dp + (size_t)i * D_INNER, yf);
    k_gemm_bf16<<<dim3(NROW / 64, 6), dim3(256), 0, stream>>>(
        yf, out_w + (size_t)i * D_MODEL * D_INNER, nullptr, hidden, D_INNER,
        D_INNER, D_MODEL, D_MODEL, 0);
  }
  // head
  k_resln<<<dim3(NROW / 4), dim3(256), 0, stream>>>(hidden, resid, resid,
                                                    gamma_f, beta_f, hn, 0, 1);
  k_pool1<<<dim3(BSZ, 14), dim3(128), 0, stream>>>(hn, partial);
  k_pool2<<<dim3(BSZ), dim3(128), 0, stream>>>(partial, pooled, x2v);
  k_head<<<dim3((NCLS + 255) / 256, BSZ), dim3(256), 0, stream>>>(pooled,
                                                                  protos, x2v,
                                                                  out);
}

// Round 4
// 3785.443 us; speedup vs baseline: 2.4011x; 1.0938x over previous
//
#include <hip/hip_runtime.h>
#include <hip/hip_bf16.h>
#include <math.h>

#define D_MODEL 384
#define D_INNER 768
#define D_STATE 16
#define DT_RANK 24
#define NXP 56          // DT_RANK + 2*D_STATE
#define LTOK 196
#define BSZ 16
#define NROW 3136       // BSZ * LTOK
#define NDEPTH 24
#define NCLS 1000

constexpr float kSqrtC   = 0.70710678118654752440f;
constexpr float kMaxNorm = 0.95f / 0.70710678118654752440f;   // 1.3435029...

typedef unsigned short u16;
typedef short  bf16x8 __attribute__((ext_vector_type(8)));
typedef u16    u16x8  __attribute__((ext_vector_type(8)));
typedef float  f32x4  __attribute__((ext_vector_type(4)));

__device__ __forceinline__ float clampf(float x, float lo, float hi) {
  return fminf(fmaxf(x, lo), hi);
}

// f32 -> bf16 (RNE)
__device__ __forceinline__ u16 f2bf(float f) {
  union { float f; unsigned u; } v; v.f = f;
  return (u16)((v.u + 0x7FFFu + ((v.u >> 16) & 1u)) >> 16);
}
// bf16 -> f32
__device__ __forceinline__ float bf2f(u16 s) {
  union { unsigned u; float f; } v; v.u = ((unsigned)s) << 16;
  return v.f;
}

// 64-lane wave reduction (no LDS, no barriers)
__device__ __forceinline__ float waveSum(float v) {
#pragma unroll
  for (int o = 1; o < 64; o <<= 1) v += __shfl_xor(v, o, 64);
  return v;
}

// block=128 sum-reduce with broadcast (stem kernels only).
__device__ __forceinline__ float blockSum128(float v, float* sm) {
#pragma unroll
  for (int o = 32; o > 0; o >>= 1) v += __shfl_down(v, o, 64);
  __syncthreads();
  if ((threadIdx.x & 63) == 0) sm[threadIdx.x >> 6] = v;
  __syncthreads();
  return sm[0] + sm[1];
}

// --------------------------- f32 -> bf16 bulk convert (weights, per call) ---
__global__ __launch_bounds__(256) void k_cvt(const float* __restrict__ s,
                                             u16* __restrict__ d, int n4) {
  int i = blockIdx.x * 256 + threadIdx.x;
  if (i >= n4) return;
  float4 v = ((const float4*)s)[i];
  short4 o = {(short)f2bf(v.x), (short)f2bf(v.y), (short)f2bf(v.z),
              (short)f2bf(v.w)};
  *(short4*)&d[(size_t)i * 4] = o;
}

// ------------------------------------------------- im2col (emit bf16) ------
__global__ __launch_bounds__(256) void k_im2col(const float* __restrict__ x,
                                                u16* __restrict__ P) {
  size_t idx = (size_t)blockIdx.x * 256 + threadIdx.x;
  if (idx >= (size_t)NROW * 768) return;
  int k = (int)(idx % 768);
  int r = (int)(idx / 768);
  int b = r / LTOK, t = r % LTOK;
  int hp = t / 14, wp = t % 14;
  int c = k / 256, rem = k % 256, i = rem / 16, j = rem % 16;
  P[idx] = f2bf(
      x[(((size_t)(b * 3 + c) * 224) + hp * 16 + i) * 224 + wp * 16 + j]);
}

// ------------------------- pure-bf16 MFMA GEMM: C = A * W^T (+bias, act) ----
// A (M,K) bf16 rm stride lda, W (Nv,K) bf16 rm stride K (tight), C stride ldc.
// Grid (M/64, Npad/64). Guards: W rows >= Nv stage 0; K tail (K%32) zero-pad;
// stores only cg < Nv. act: 0 none, 1 softplus(+bias), 2 silu if cg>=768.
// obf: 1 -> store bf16 into (u16*)C, else f32.
#define LDA 40
__global__ __launch_bounds__(256) void k_gemm_bb(
    const u16* __restrict__ A, const u16* __restrict__ W,
    const float* __restrict__ bias, void* __restrict__ Cv, int K, int lda,
    int ldc, int Nv, int act, int obf) {
  __shared__ u16 As[64 * LDA];
  __shared__ u16 Ws[64 * LDA];
  const int tid = threadIdx.x;
  const int m0 = blockIdx.x * 64;
  const int n0 = blockIdx.y * 64;
  const int lane = tid & 63;
  const int wave = tid >> 6;
  const int wm = wave & 1, wn = wave >> 1;
  const int lm = lane & 15;
  const int quad = lane >> 4;
  const int srow = tid >> 2;
  const int sseg = tid & 3;

  f32x4 acc[2][2];
#pragma unroll
  for (int i = 0; i < 2; i++)
#pragma unroll
    for (int j = 0; j < 2; j++) acc[i][j] = (f32x4){0.f, 0.f, 0.f, 0.f};

  const u16* rowA = A + (size_t)(m0 + srow) * lda + sseg * 8;
  const int wrow = n0 + srow;
  const u16* rowW = W + (size_t)wrow * K + sseg * 8;
  const bool wvalid = wrow < Nv;

  for (int k0 = 0; k0 < K; k0 += 32) {
    u16x8 av = {0, 0, 0, 0, 0, 0, 0, 0}, wv = {0, 0, 0, 0, 0, 0, 0, 0};
    if (k0 + 32 <= K) {
      av = *(const u16x8*)(rowA + k0);
      if (wvalid) wv = *(const u16x8*)(rowW + k0);
    } else {
#pragma unroll
      for (int kk = 0; kk < 8; kk++) {
        int k = k0 + sseg * 8 + kk;
        if (k < K) {
          av[kk] = rowA[k - sseg * 8];
          if (wvalid) wv[kk] = rowW[k - sseg * 8];
        }
      }
    }
    __syncthreads();  // guard LDS reuse from previous iter's reads
    *(u16x8*)&As[srow * LDA + sseg * 8] = av;
    *(u16x8*)&Ws[srow * LDA + sseg * 8] = wv;
    __syncthreads();
    bf16x8 af[2], bfr[2];
#pragma unroll
    for (int i = 0; i < 2; i++) {
      af[i]  = *(bf16x8*)&As[(wm * 32 + i * 16 + lm) * LDA + quad * 8];
      bfr[i] = *(bf16x8*)&Ws[(wn * 32 + i * 16 + lm) * LDA + quad * 8];
    }
#pragma unroll
    for (int i = 0; i < 2; i++)
#pragma unroll
      for (int j = 0; j < 2; j++)
        acc[i][j] = __builtin_amdgcn_mfma_f32_16x16x32_bf16(af[i], bfr[j],
                                                            acc[i][j], 0, 0, 0);
  }
  // epilogue: C/D layout col=lane&15, row=quad*4+reg
#pragma unroll
  for (int i = 0; i < 2; i++) {
#pragma unroll
    for (int j = 0; j < 2; j++) {
      int cg = n0 + wn * 32 + j * 16 + lm;
      if (cg >= Nv) continue;
      float bj = bias ? bias[cg] : 0.f;
#pragma unroll
      for (int reg = 0; reg < 4; reg++) {
        int rg = m0 + wm * 32 + i * 16 + quad * 4 + reg;
        float o = acc[i][j][reg] + bj;
        if (act == 1) o = (o > 20.f) ? o : log1pf(expf(o));
        else if (act == 2 && cg >= 768) o = o / (1.f + expf(-o));
        if (obf) ((u16*)Cv)[(size_t)rg * ldc + cg] = f2bf(o);
        else ((float*)Cv)[(size_t)rg * ldc + cg] = o;
      }
    }
  }
}

// ------------------ stem a: expmap0(tokens) -> bf16 h + ||h|| ---------------
__global__ __launch_bounds__(128) void k_stem_a(const float* __restrict__ tok,
                                                u16* __restrict__ hb,
                                                float* __restrict__ xn) {
  __shared__ float sm[2];
  const int r = blockIdx.x, tid = threadIdx.x;
  float v[3];
#pragma unroll
  for (int j = 0; j < 3; j++) v[j] = tok[(size_t)r * D_MODEL + tid + j * 128];
  float s = blockSum128(v[0] * v[0] + v[1] * v[1] + v[2] * v[2], sm);
  float n = sqrtf(s + 1e-15f);
  float nc = clampf(n, 1e-8f, 5.f);
  float ke = tanhf(kSqrtC * nc) / (kSqrtC * nc);
  float rn = sqrtf(ke * ke * s + 1e-15f);
  float sc = rn > kMaxNorm ? kMaxNorm / rn : 1.f;
  float kk = ke * sc;
#pragma unroll
  for (int j = 0; j < 3; j++)
    hb[(size_t)r * D_MODEL + tid + j * 128] = f2bf(kk * v[j]);
  if (tid == 0) xn[r] = fmaxf(sqrtf(kk * kk * s + 1e-15f), 1e-8f);
}

// --- stem b: mobius_matvec tail + mobius_add(hyp_b) + hyp_LN + pos + expmap -
__global__ __launch_bounds__(128) void k_stem_b(
    const float* __restrict__ mx, const float* __restrict__ xn,
    const float* __restrict__ hyp_b, const float* __restrict__ pe_g,
    const float* __restrict__ pe_b, const float* __restrict__ pos,
    float* __restrict__ outh) {
  __shared__ float sm[2];
  const int r = blockIdx.x, tid = threadIdx.x;
  const int t = r % LTOK;
  float mv[3], bv[3];
  int dd[3];
#pragma unroll
  for (int j = 0; j < 3; j++) {
    dd[j] = tid + j * 128;
    mv[j] = mx[(size_t)r * D_MODEL + dd[j]];
    bv[j] = hyp_b[dd[j]];
  }
  float smx = blockSum128(mv[0] * mv[0] + mv[1] * mv[1] + mv[2] * mv[2], sm);
  float mxn = fmaxf(sqrtf(smx + 1e-15f), 1e-8f);
  float xnv = xn[r];
  float tt = tanhf(mxn / xnv * atanhf(fminf(kSqrtC * xnv, 1.f - 1e-5f)));
  float kres = tt / (mxn * kSqrtC);
  float res[3];
#pragma unroll
  for (int j = 0; j < 3; j++) res[j] = kres * mv[j];
  float xy = blockSum128(res[0] * bv[0] + res[1] * bv[1] + res[2] * bv[2], sm);
  float y2 = blockSum128(bv[0] * bv[0] + bv[1] * bv[1] + bv[2] * bv[2], sm);
  float x2 = kres * kres * smx;
  float al = 1.f + xy + 0.5f * y2;
  float be = 1.f - 0.5f * x2;
  float den = fmaxf(1.f + xy + 0.25f * x2 * y2, 1e-15f);
  float h1[3];
#pragma unroll
  for (int j = 0; j < 3; j++) h1[j] = (al * res[j] + be * bv[j]) / den;
  float s1 = blockSum128(h1[0] * h1[0] + h1[1] * h1[1] + h1[2] * h1[2], sm);
  float n1 = sqrtf(s1 + 1e-15f);
  float nc1 = clampf(n1, 1e-8f, kMaxNorm);
  float kl = atanhf(fminf(kSqrtC * nc1, 0.95f)) / (kSqrtC * nc1);
  float tl[3];
#pragma unroll
  for (int j = 0; j < 3; j++) tl[j] = kl * h1[j];
  float mean = blockSum128(tl[0] + tl[1] + tl[2], sm) * (1.f / 384.f);
  float dv = 0.f;
#pragma unroll
  for (int j = 0; j < 3; j++) { float d = tl[j] - mean; dv += d * d; }
  float var = blockSum128(dv, sm) * (1.f / 383.f);
  float inv = 1.f / (sqrtf(var) + 1e-5f);
  float g[3];
#pragma unroll
  for (int j = 0; j < 3; j++)
    g[j] = (tl[j] - mean) * inv * pe_g[dd[j]] + pe_b[dd[j]];
  float sg = blockSum128(g[0] * g[0] + g[1] * g[1] + g[2] * g[2], sm);
  float ng = sqrtf(sg + 1e-15f);
  float nc2 = clampf(ng, 1e-8f, 5.f);
  float ke = tanhf(kSqrtC * nc2) / (kSqrtC * nc2);
  float rn = sqrtf(ke * ke * sg + 1e-15f);
  float sc = rn > kMaxNorm ? kMaxNorm / rn : 1.f;
  float kk = ke * sc;
  float s2 = kk * kk * sg;
  float n3 = sqrtf(s2 + 1e-15f);
  float nc3 = clampf(n3, 1e-8f, kMaxNorm);
  float kl2 = atanhf(fminf(kSqrtC * nc3, 0.95f)) / (kSqrtC * nc3);
  float v[3];
#pragma unroll
  for (int j = 0; j < 3; j++)
    v[j] = kl2 * kk * g[j] + pos[(size_t)t * D_MODEL + dd[j]];
  float sv = blockSum128(v[0] * v[0] + v[1] * v[1] + v[2] * v[2], sm);
  float nv = sqrtf(sv + 1e-15f);
  float nc4 = clampf(nv, 1e-8f, 5.f);
  float ke2 = tanhf(kSqrtC * nc4) / (kSqrtC * nc4);
  float rn2 = sqrtf(ke2 * ke2 * sv + 1e-15f);
  float sc2 = rn2 > kMaxNorm ? kMaxNorm / rn2 : 1.f;
#pragma unroll
  for (int j = 0; j < 3; j++)
    outh[(size_t)r * D_MODEL + dd[j]] = ke2 * sc2 * v[j];
}

// --- residual accumulate + hyp_layernorm, one wave per row (no barriers) ----
// out_logmap==0: write bf16 to out_bf.  out_logmap==1: write f32 to out_f.
__global__ __launch_bounds__(256) void k_resln(
    const float* __restrict__ hid, const float* __restrict__ res_in,
    float* __restrict__ res_out, const float* __restrict__ g_,
    const float* __restrict__ b_, u16* __restrict__ out_bf,
    float* __restrict__ out_f, int first, int out_logmap) {
  const int lane = threadIdx.x & 63;
  const int r = blockIdx.x * 4 + (threadIdx.x >> 6);
  float v[6];
  int dd[6];
#pragma unroll
  for (int j = 0; j < 6; j++) {
    dd[j] = lane + j * 64;
    size_t idx = (size_t)r * D_MODEL + dd[j];
    v[j] = hid[idx] + (first ? 0.f : res_in[idx]);
    res_out[idx] = v[j];
  }
  float ss = 0.f;
#pragma unroll
  for (int j = 0; j < 6; j++) ss += v[j] * v[j];
  float s = waveSum(ss);
  float n = sqrtf(s + 1e-15f);
  float nc = clampf(n, 1e-8f, kMaxNorm);
  float kl = atanhf(fminf(kSqrtC * nc, 0.95f)) / (kSqrtC * nc);
  float t[6];
  float ts = 0.f;
#pragma unroll
  for (int j = 0; j < 6; j++) { t[j] = kl * v[j]; ts += t[j]; }
  float mean = waveSum(ts) * (1.f / 384.f);
  float dv = 0.f;
#pragma unroll
  for (int j = 0; j < 6; j++) { float d = t[j] - mean; dv += d * d; }
  float var = waveSum(dv) * (1.f / 383.f);
  float inv = 1.f / (sqrtf(var) + 1e-5f);
  float g[6];
  float gs = 0.f;
#pragma unroll
  for (int j = 0; j < 6; j++) {
    g[j] = (t[j] - mean) * inv * g_[dd[j]] + b_[dd[j]];
    gs += g[j] * g[j];
  }
  float sg = waveSum(gs);
  float ng = sqrtf(sg + 1e-15f);
  float nc2 = clampf(ng, 1e-8f, 5.f);
  float ke = tanhf(kSqrtC * nc2) / (kSqrtC * nc2);
  float rn = sqrtf(ke * ke * sg + 1e-15f);
  float sc = rn > kMaxNorm ? kMaxNorm / rn : 1.f;
  float kk = ke * sc;
  if (!out_logmap) {
#pragma unroll
    for (int j = 0; j < 6; j++)
      out_bf[(size_t)r * D_MODEL + dd[j]] = f2bf(kk * g[j]);
  } else {
    float s2 = kk * kk * sg;
    float n3 = sqrtf(s2 + 1e-15f);
    float nc3 = clampf(n3, 1e-8f, kMaxNorm);
    float kl2 = atanhf(fminf(kSqrtC * nc3, 0.95f)) / (kSqrtC * nc3);
#pragma unroll
    for (int j = 0; j < 6; j++)
      out_f[(size_t)r * D_MODEL + dd[j]] = kl2 * kk * g[j];
  }
}

// ------------- conv1d(k=4, causal) + SiLU, bf16 in/out, 8 ch/thread ---------
__global__ __launch_bounds__(256) void k_conv(const u16* __restrict__ xz,
                                              const float* __restrict__ cw,
                                              const float* __restrict__ cb,
                                              u16* __restrict__ u) {
  int idx = blockIdx.x * 256 + threadIdx.x;   // NROW*96 total
  if (idx >= NROW * 96) return;
  int d8 = idx % 96, r = idx / 96;
  int b = r / LTOK, l = r % LTOK;
  float acc[8];
#pragma unroll
  for (int t = 0; t < 8; t++) acc[t] = cb[d8 * 8 + t];
#pragma unroll
  for (int k = 0; k < 4; k++) {
    int ll = l - 3 + k;
    if (ll >= 0) {
      u16x8 xv = *(const u16x8*)(xz + (size_t)(b * LTOK + ll) * (2 * D_INNER) +
                                 d8 * 8);
#pragma unroll
      for (int t = 0; t < 8; t++)
        acc[t] = fmaf(cw[(d8 * 8 + t) * 4 + k], bf2f(xv[t]), acc[t]);
    }
  }
  u16x8 o;
#pragma unroll
  for (int t = 0; t < 8; t++) o[t] = f2bf(acc[t] / (1.f + expf(-acc[t])));
  *(u16x8*)(u + (size_t)r * D_INNER + d8 * 8) = o;
}

// ------ selective scan, (b,d,n)-parallel, chunked double-buffered prefetch --
// bf16 u/z/B/C, f32 dt; bf16 yf out.
#define SCH 7
#define NCH 28   // 28*7 = 196
#define LOADC(dtA, uA, BA, CA, zA, c)                                   \
  do {                                                                  \
    _Pragma("unroll") for (int j = 0; j < SCH; j++) {                   \
      size_t r = base + (size_t)(c) * SCH + j;                          \
      dtA[j] = dtbuf[r * D_INNER + d];                                  \
      uA[j]  = bf2f(u[r * D_INNER + d]);                                \
      BA[j]  = bf2f(dbl[r * NXP + DT_RANK + n]);                        \
      CA[j]  = bf2f(dbl[r * NXP + DT_RANK + D_STATE + n]);              \
      zA[j]  = bf2f(xz[r * (2 * D_INNER) + D_INNER + d]);               \
    }                                                                   \
  } while (0)
#define COMPC(dtA, uA, BA, CA, zA, c)                                   \
  do {                                                                  \
    float dA[SCH], bu[SCH];                                             \
    _Pragma("unroll") for (int j = 0; j < SCH; j++) {                   \
      dA[j] = expf(dtA[j] * a);                                         \
      bu[j] = dtA[j] * BA[j] * uA[j];                                   \
    }                                                                   \
    _Pragma("unroll") for (int j = 0; j < SCH; j++) {                   \
      h = fmaf(dA[j], h, bu[j]);                                        \
      float y = h * CA[j];                                              \
      y += __shfl_xor(y, 1, 64);                                        \
      y += __shfl_xor(y, 2, 64);                                        \
      y += __shfl_xor(y, 4, 64);                                        \
      y += __shfl_xor(y, 8, 64);                                        \
      if (n == 0) {                                                     \
        size_t r = base + (size_t)(c) * SCH + j;                        \
        yf[r * D_INNER + d] = f2bf(fmaf(Dv, uA[j], y) * zA[j]);         \
      }                                                                 \
    }                                                                   \
  } while (0)

__global__ __launch_bounds__(256, 3) void k_scan(
    const u16* __restrict__ u, const float* __restrict__ dtbuf,
    const u16* __restrict__ dbl, const u16* __restrict__ xz,
    const float* __restrict__ A_log, const float* __restrict__ Dp,
    u16* __restrict__ yf) {
  const int tid = threadIdx.x;
  const int n = tid & 15, dl = tid >> 4;
  const int d = blockIdx.x * 16 + dl;
  const int b = blockIdx.y;
  const float a = -expf(A_log[(size_t)d * D_STATE + n]);
  const float Dv = Dp[d];
  const size_t base = (size_t)b * LTOK;
  float h = 0.f;
  float dt0[SCH], u0[SCH], B0[SCH], C0[SCH], z0[SCH];
  float dt1[SCH], u1[SCH], B1[SCH], C1[SCH], z1[SCH];
  LOADC(dt0, u0, B0, C0, z0, 0);
  for (int c = 0; c < NCH; c += 2) {
    LOADC(dt1, u1, B1, C1, z1, c + 1);
    COMPC(dt0, u0, B0, C0, z0, c);
    if (c + 2 < NCH) LOADC(dt0, u0, B0, C0, z0, c + 2);
    COMPC(dt1, u1, B1, C1, z1, c + 1);
  }
}

// ---------------------- pool phase 1: partial sums over 14-token chunks -----
__global__ __launch_bounds__(128) void k_pool1(const float* __restrict__ tl,
                                               float* __restrict__ partial) {
  const int b = blockIdx.x, g = blockIdx.y, tid = threadIdx.x;
  float m[3] = {0.f, 0.f, 0.f};
  for (int l = g * 14; l < (g + 1) * 14; l++) {
    size_t row = ((size_t)b * LTOK + l) * D_MODEL;
#pragma unroll
    for (int j = 0; j < 3; j++) m[j] += tl[row + tid + j * 128];
  }
#pragma unroll
  for (int j = 0; j < 3; j++)
    partial[((size_t)b * 14 + g) * D_MODEL + tid + j * 128] = m[j];
}

// ------------------ pool phase 2: finalize mean + expmap0 -------------------
__global__ __launch_bounds__(128) void k_pool2(const float* __restrict__ partial,
                                               float* __restrict__ pooled,
                                               float* __restrict__ x2v) {
  __shared__ float sm[2];
  const int b = blockIdx.x, tid = threadIdx.x;
  float m[3] = {0.f, 0.f, 0.f};
  for (int g = 0; g < 14; g++) {
    size_t row = ((size_t)b * 14 + g) * D_MODEL;
#pragma unroll
    for (int j = 0; j < 3; j++) m[j] += partial[row + tid + j * 128];
  }
#pragma unroll
  for (int j = 0; j < 3; j++) m[j] *= (1.f / (float)LTOK);
  float s = blockSum128(m[0] * m[0] + m[1] * m[1] + m[2] * m[2], sm);
  float n = sqrtf(s + 1e-15f);
  float nc = clampf(n, 1e-8f, 5.f);
  float ke = tanhf(kSqrtC * nc) / (kSqrtC * nc);
  float rn = sqrtf(ke * ke * s + 1e-15f);
  float sc = rn > kMaxNorm ? kMaxNorm / rn : 1.f;
  float kk = ke * sc;
  float p[3];
#pragma unroll
  for (int j = 0; j < 3; j++) {
    p[j] = kk * m[j];
    pooled[(size_t)b * D_MODEL + tid + j * 128] = p[j];
  }
  float s2 = blockSum128(p[0] * p[0] + p[1] * p[1] + p[2] * p[2], sm);
  if (tid == 0) x2v[b] = s2;
}

// ------------------- hyperbolic distance head over prototypes ---------------
__global__ __launch_bounds__(256) void k_head(const float* __restrict__ pooled,
                                              const float* __restrict__ protos,
                                              const float* __restrict__ x2v,
                                              float* __restrict__ out) {
  __shared__ float sp[D_MODEL];
  const int b = blockIdx.y;
  const int c = blockIdx.x * 256 + threadIdx.x;
  for (int j = threadIdx.x; j < D_MODEL; j += 256)
    sp[j] = pooled[(size_t)b * D_MODEL + j];
  __syncthreads();
  if (c >= NCLS) return;
  const float* pr = protos + (size_t)c * D_MODEL;
  float dotv = 0.f, y2 = 0.f;
  for (int k = 0; k < D_MODEL; k++) {
    float w = pr[k];
    dotv += sp[k] * w;
    y2 += w * w;
  }
  float x2 = x2v[b];
  float xy = -dotv;
  float al = 1.f + xy + 0.5f * y2;
  float be = 1.f - 0.5f * x2;
  float num2 = al * al * x2 + 2.f * al * be * xy + be * be * y2;
  float den = fmaxf(1.f + xy + 0.25f * x2 * y2, 1e-15f);
  float r2 = num2 / (den * den) + 1e-15f;
  float dn = fminf(kSqrtC * sqrtf(r2), 1.f - 1e-5f);
  out[(size_t)b * NCLS + c] = -(2.f / kSqrtC) * atanhf(dn);
}

// ---------------------------------------------------------------------------
extern "C" void kernel_launch(void* const* d_in, const int* in_sizes, int n_in,
                              void* d_out, int out_size, void* d_ws,
                              size_t ws_size, hipStream_t stream) {
  const float* x        = (const float*)d_in[0];
  const float* patch_w  = (const float*)d_in[1];
  const float* patch_b  = (const float*)d_in[2];
  const float* hyp_w    = (const float*)d_in[3];
  const float* hyp_b    = (const float*)d_in[4];
  const float* pe_gamma = (const float*)d_in[5];
  const float* pe_beta  = (const float*)d_in[6];
  const float* pos      = (const float*)d_in[7];
  const float* in_w     = (const float*)d_in[8];
  const float* conv_w   = (const float*)d_in[9];
  const float* conv_b   = (const float*)d_in[10];
  const float* xp_w     = (const float*)d_in[11];
  const float* dt_w     = (const float*)d_in[12];
  const float* dt_bias  = (const float*)d_in[13];
  const float* A_log    = (const float*)d_in[14];
  const float* Dp       = (const float*)d_in[15];
  const float* out_w    = (const float*)d_in[16];
  const float* gamma    = (const float*)d_in[17];
  const float* beta     = (const float*)d_in[18];
  const float* gamma_f  = (const float*)d_in[19];
  const float* beta_f   = (const float*)d_in[20];
  const float* protos   = (const float*)d_in[21];
  float* out = (float*)d_out;

  // ---- workspace layout (bytes, 256-aligned chunks); ~88 MB total ----
  char* cur = (char*)d_ws;
  auto alloc = [&](size_t bytes) {
    char* p = cur;
    cur += (bytes + 255) & ~(size_t)255;
    return (void*)p;
  };
  float* hidden  = (float*)alloc((size_t)NROW * D_MODEL * 4);
  float* resid   = (float*)alloc((size_t)NROW * D_MODEL * 4);
  float* dtbuf   = (float*)alloc((size_t)NROW * D_INNER * 4);
  float* xn      = (float*)alloc((size_t)NROW * 4);
  float* pooled  = (float*)alloc((size_t)BSZ * D_MODEL * 4);
  float* x2v     = (float*)alloc((size_t)BSZ * 4);
  float* partial = (float*)alloc((size_t)BSZ * 14 * D_MODEL * 4);
  u16* hn_bf  = (u16*)alloc((size_t)NROW * D_MODEL * 2);
  u16* xz_bf  = (u16*)alloc((size_t)NROW * 2 * D_INNER * 2);
  u16* u_bf   = (u16*)alloc((size_t)NROW * D_INNER * 2);
  u16* dbl_bf = (u16*)alloc((size_t)NROW * NXP * 2);
  u16* yf_bf  = (u16*)alloc((size_t)NROW * D_INNER * 2);
  // bf16 weights
  const size_t n_inw  = (size_t)NDEPTH * 2 * D_INNER * D_MODEL;   // 14.2M
  const size_t n_outw = (size_t)NDEPTH * D_MODEL * D_INNER;       // 7.1M
  const size_t n_xpw  = (size_t)NDEPTH * NXP * D_INNER;           // 1.0M
  const size_t n_dtw  = (size_t)NDEPTH * D_INNER * DT_RANK;       // 0.44M
  const size_t n_pw   = (size_t)D_MODEL * 768;
  const size_t n_hw   = (size_t)D_MODEL * D_MODEL;
  u16* in_wb  = (u16*)alloc(n_inw * 2);
  u16* out_wb = (u16*)alloc(n_outw * 2);
  u16* xp_wb  = (u16*)alloc(n_xpw * 2);
  u16* dt_wb  = (u16*)alloc(n_dtw * 2);
  u16* p_wb   = (u16*)alloc(n_pw * 2);
  u16* h_wb   = (u16*)alloc(n_hw * 2);
  // stem/head aliases over dead regions
  u16* P_bf    = xz_bf;                       // 3136x768 bf16 im2col
  float* tokens = dtbuf;                      // 3136x384 f32
  float* mx     = dtbuf + (size_t)NROW * D_MODEL;  // 3136x384 f32
  float* hnf    = dtbuf;                      // head: f32 logmap rows

  // ---- weight conversion (every call; ws is re-poisoned by harness) ----
  k_cvt<<<dim3((int)((n_inw / 4 + 255) / 256)), dim3(256), 0, stream>>>(
      in_w, in_wb, (int)(n_inw / 4));
  k_cvt<<<dim3((int)((n_outw / 4 + 255) / 256)), dim3(256), 0, stream>>>(
      out_w, out_wb, (int)(n_outw / 4));
  k_cvt<<<dim3((int)((n_xpw / 4 + 255) / 256)), dim3(256), 0, stream>>>(
      xp_w, xp_wb, (int)(n_xpw / 4));
  k_cvt<<<dim3((int)((n_dtw / 4 + 255) / 256)), dim3(256), 0, stream>>>(
      dt_w, dt_wb, (int)(n_dtw / 4));
  k_cvt<<<dim3((int)((n_pw / 4 + 255) / 256)), dim3(256), 0, stream>>>(
      patch_w, p_wb, (int)(n_pw / 4));
  k_cvt<<<dim3((int)((n_hw / 4 + 255) / 256)), dim3(256), 0, stream>>>(
      hyp_w, h_wb, (int)(n_hw / 4));

  // ---- stem ----
  k_im2col<<<dim3((NROW * 768) / 256), dim3(256), 0, stream>>>(x, P_bf);
  k_gemm_bb<<<dim3(NROW / 64, 6), dim3(256), 0, stream>>>(
      P_bf, p_wb, patch_b, tokens, 768, 768, D_MODEL, D_MODEL, 0, 0);
  k_stem_a<<<dim3(NROW), dim3(128), 0, stream>>>(tokens, hn_bf, xn);
  k_gemm_bb<<<dim3(NROW / 64, 6), dim3(256), 0, stream>>>(
      hn_bf, h_wb, nullptr, mx, D_MODEL, D_MODEL, D_MODEL, D_MODEL, 0, 0);
  k_stem_b<<<dim3(NROW), dim3(128), 0, stream>>>(mx, xn, hyp_b, pe_gamma,
                                                 pe_beta, pos, hidden);
  // ---- layers ----
  for (int i = 0; i < NDEPTH; i++) {
    k_resln<<<dim3(NROW / 4), dim3(256), 0, stream>>>(
        hidden, resid, resid, gamma + (size_t)i * D_MODEL,
        beta + (size_t)i * D_MODEL, hn_bf, nullptr, i == 0 ? 1 : 0, 0);
    // in_proj (z-half gets SiLU fused: act=2), bf16 out
    k_gemm_bb<<<dim3(NROW / 64, 24), dim3(256), 0, stream>>>(
        hn_bf, in_wb + (size_t)i * 2 * D_INNER * D_MODEL, nullptr, xz_bf,
        D_MODEL, D_MODEL, 2 * D_INNER, 2 * D_INNER, 2, 1);
    k_conv<<<dim3((NROW * 96 + 255) / 256), dim3(256), 0, stream>>>(
        xz_bf, conv_w + (size_t)i * D_INNER * 4, conv_b + (size_t)i * D_INNER,
        u_bf);
    // x_proj: N 56 padded to 64, bf16 out
    k_gemm_bb<<<dim3(NROW / 64, 1), dim3(256), 0, stream>>>(
        u_bf, xp_wb + (size_t)i * NXP * D_INNER, nullptr, dbl_bf, D_INNER,
        D_INNER, NXP, NXP, 0, 1);
    // dt_proj: K=24 zero-padded to 32, softplus+bias epilogue, f32 out
    k_gemm_bb<<<dim3(NROW / 64, 12), dim3(256), 0, stream>>>(
        dbl_bf, dt_wb + (size_t)i * D_INNER * DT_RANK,
        dt_bias + (size_t)i * D_INNER, dtbuf, DT_RANK, NXP, D_INNER, D_INNER,
        1, 0);
    k_scan<<<dim3(D_INNER / 16, BSZ), dim3(256), 0, stream>>>(
        u_bf, dtbuf, dbl_bf, xz_bf, A_log + (size_t)i * D_INNER * D_STATE,
        Dp + (size_t)i * D_INNER, yf_bf);
    k_gemm_bb<<<dim3(NROW / 64, 6), dim3(256), 0, stream>>>(
        yf_bf, out_wb + (size_t)i * D_MODEL * D_INNER, nullptr, hidden,
        D_INNER, D_INNER, D_MODEL, D_MODEL, 0, 0);
  }
  // ---- head ----
  k_resln<<<dim3(NROW / 4), dim3(256), 0, stream>>>(
      hidden, resid, resid, gamma_f, beta_f, nullptr, hnf, 0, 1);
  k_pool1<<<dim3(BSZ, 14), dim3(128), 0, stream>>>(hnf, partial);
  k_pool2<<<dim3(BSZ), dim3(128), 0, stream>>>(partial, pooled, x2v);
  k_head<<<dim3((NCLS + 255) / 256, BSZ), dim3(256), 0, stream>>>(pooled,
                                                                  protos, x2v,
                                                                  out);
}